// Round 5
// baseline (746.392 us; speedup 1.0000x reference)
//
#include <hip/hip_runtime.h>

typedef float f32x4 __attribute__((ext_vector_type(4)));
typedef __bf16 bf16x8 __attribute__((ext_vector_type(8)));
typedef _Float16 f16x8 __attribute__((ext_vector_type(8)));
typedef short s16x8 __attribute__((ext_vector_type(8)));
typedef unsigned short u16;

#define DEV static __device__ __forceinline__

#define SEL_BAND 2.0e-3f   // fp16-GEMM1 error band for exact re-ranking

DEV u16 f2bf_rn(float f) {
    unsigned u = __float_as_uint(f);
    return (u16)((u + 0x7fffu + ((u >> 16) & 1u)) >> 16);
}

typedef __attribute__((address_space(3))) unsigned int lds_u32;
typedef __attribute__((address_space(1))) const unsigned int glb_u32;

DEV void gload16(const void* g, void* l) {
    __builtin_amdgcn_global_load_lds((glb_u32*)g, (lds_u32*)l, 16, 0, 0);
}

// ---------------- X f32 -> fp16 (unscaled) ----------------
__global__ __launch_bounds__(256) void xcvt(const float* __restrict__ X, u16* __restrict__ Xh, int n8) {
    int i = blockIdx.x * 256 + threadIdx.x;
    int stride = gridDim.x * 256;
    for (; i < n8; i += stride) {
        f32x4 a = ((const f32x4*)X)[2 * i];
        f32x4 b = ((const f32x4*)X)[2 * i + 1];
        u16 h[8];
#pragma unroll
        for (int j = 0; j < 4; j++) {
            h[j]     = __builtin_bit_cast(u16, (_Float16)a[j]);
            h[j + 4] = __builtin_bit_cast(u16, (_Float16)b[j]);
        }
        ((uint4*)Xh)[i] = make_uint4((unsigned)h[0] | ((unsigned)h[1] << 16),
                                     (unsigned)h[2] | ((unsigned)h[3] << 16),
                                     (unsigned)h[4] | ((unsigned)h[5] << 16),
                                     (unsigned)h[6] | ((unsigned)h[7] << 16));
    }
}

// ---------------- transpose [R][C] f32 -> [C][R] fp16*256 ----------------
__global__ __launch_bounds__(256) void tr_h(const float* __restrict__ src, int R, int C,
                                            u16* __restrict__ hT) {
    __shared__ float t[32][33];
    int tx = threadIdx.x, ty = threadIdx.y;
    int c0 = blockIdx.x * 32, r0 = blockIdx.y * 32;
#pragma unroll
    for (int i = 0; i < 4; i++) t[ty + i * 8][tx] = src[(size_t)(r0 + ty + i * 8) * C + c0 + tx];
    __syncthreads();
#pragma unroll
    for (int i = 0; i < 4; i++) {
        int c = c0 + ty + i * 8;
        float v = t[tx][ty + i * 8];
        hT[(size_t)c * R + r0 + tx] = __builtin_bit_cast(u16, (_Float16)(v * 256.0f));
    }
}

// ---------------- transpose [R][C] f32 -> [C][R] f32 ----------------
__global__ __launch_bounds__(256) void tr_f32(const float* __restrict__ src, int R, int C,
                                              float* __restrict__ dst) {
    __shared__ float t[32][33];
    int tx = threadIdx.x, ty = threadIdx.y;
    int c0 = blockIdx.x * 32, r0 = blockIdx.y * 32;
#pragma unroll
    for (int i = 0; i < 4; i++) t[ty + i * 8][tx] = src[(size_t)(r0 + ty + i * 8) * C + c0 + tx];
    __syncthreads();
#pragma unroll
    for (int i = 0; i < 4; i++)
        dst[(size_t)(c0 + ty + i * 8) * R + r0 + tx] = t[tx][ty + i * 8];
}

// ---------------- transpose [R][C] f32 -> [C][R] fp16*256 + f32 (fallback combined) ----------------
__global__ __launch_bounds__(256) void tr_hf(const float* __restrict__ src, int R, int C,
                                             u16* __restrict__ hT, float* __restrict__ fT) {
    __shared__ float t[32][33];
    int tx = threadIdx.x, ty = threadIdx.y;
    int c0 = blockIdx.x * 32, r0 = blockIdx.y * 32;
#pragma unroll
    for (int i = 0; i < 4; i++) t[ty + i * 8][tx] = src[(size_t)(r0 + ty + i * 8) * C + c0 + tx];
    __syncthreads();
#pragma unroll
    for (int i = 0; i < 4; i++) {
        int c = c0 + ty + i * 8;
        float v = t[tx][ty + i * 8];
        size_t o = (size_t)c * R + r0 + tx;
        hT[o] = __builtin_bit_cast(u16, (_Float16)(v * 256.0f));
        fT[o] = v;
    }
}

// ---------------- transpose [R][C] f32 -> [C][R] bf16 ----------------
__global__ __launch_bounds__(256) void tr_bf16(const float* __restrict__ src, int R, int C,
                                               u16* __restrict__ dst) {
    __shared__ float t[32][33];
    int tx = threadIdx.x, ty = threadIdx.y;
    int c0 = blockIdx.x * 32, r0 = blockIdx.y * 32;
#pragma unroll
    for (int i = 0; i < 4; i++) t[ty + i * 8][tx] = src[(size_t)(r0 + ty + i * 8) * C + c0 + tx];
    __syncthreads();
#pragma unroll
    for (int i = 0; i < 4; i++)
        dst[(size_t)(c0 + ty + i * 8) * R + r0 + tx] = f2bf_rn(t[tx][ty + i * 8]);
}

// ---------------- m97-structure GEMM: 128x128, BK=64, 4 waves, single-buffer ----------------
// DT 0: f16 MFMA, epi = acc/256 + bias, relu, f32 out   (gemm1)
// DT 1: bf16 MFMA, epi = relu -> bf16 out                (gemm2)
// DT 2: bf16 MFMA, epi = sigmoid -> f32 out              (gemm3)
// AF32: A source is f32, reg-staged cvt->f16 into LDS (fallback gemm1 only).
template <int DT, bool AF32>
__global__ __launch_bounds__(256) void gemm_t(const void* __restrict__ Ap,
                                              const u16* __restrict__ BT,
                                              const float* __restrict__ bias,
                                              void* __restrict__ Out,
                                              int M, int N, int K) {
    __shared__ __align__(16) u16 As[128][64];
    __shared__ __align__(16) u16 Bs[128][64];
    int tid = threadIdx.x, lane = tid & 63, wid = tid >> 6;
    int wr = wid >> 1, wc = wid & 1;

    // bijective XCD swizzle (all grids have nwg % 8 == 0), N-major chunking
    int lin = blockIdx.x + gridDim.x * blockIdx.y;
    int nwg = gridDim.x * gridDim.y;
    int q = nwg >> 3;
    int logical = (lin & 7) * q + (lin >> 3);
    int Ny = N >> 7;
    int mb = logical / Ny, nb = logical - mb * Ny;
    int m0 = mb * 128, n0 = nb * 128;

    f32x4 acc[4][4] = {};
    int NT = K >> 6;
    for (int t = 0; t < NT; ++t) {
        int k0 = t << 6;
        if (AF32) {
            const float* Af = (const float*)Ap;
#pragma unroll
            for (int i = 0; i < 8; i++) {
                int s = i * 256 + tid;
                int r = s >> 4, qd = s & 15;
                f32x4 v = *(const f32x4*)(Af + (size_t)(m0 + r) * K + k0 + qd * 4);
                u16 h[4];
#pragma unroll
                for (int j = 0; j < 4; j++) h[j] = __builtin_bit_cast(u16, (_Float16)v[j]);
                int g = qd >> 1;
                int dst = ((g ^ r) & 7) * 16 + (qd & 1) * 8;
                *(uint2*)((char*)&As[r][0] + dst) =
                    make_uint2((unsigned)h[0] | ((unsigned)h[1] << 16),
                               (unsigned)h[2] | ((unsigned)h[3] << 16));
            }
        } else {
            const u16* Au = (const u16*)Ap;
#pragma unroll
            for (int i = 0; i < 4; i++) {
                int s = i * 256 + tid;
                int r = s >> 3, g = s & 7;
                int gs = (g ^ r) & 7;
                gload16(Au + (size_t)(m0 + r) * K + k0 + gs * 8, &As[r][g * 8]);
            }
        }
#pragma unroll
        for (int i = 0; i < 4; i++) {
            int s = i * 256 + tid;
            int r = s >> 3, g = s & 7;
            int gs = (g ^ r) & 7;
            gload16(BT + (size_t)(n0 + r) * K + k0 + gs * 8, &Bs[r][g * 8]);
        }
        __syncthreads();
#pragma unroll
        for (int kk = 0; kk < 2; kk++) {
            int gb = kk * 4 + (lane >> 4);   // K-granule index 0..7
            s16x8 af[4], bf[4];
#pragma unroll
            for (int mi = 0; mi < 4; mi++) {
                int r = wr * 64 + mi * 16 + (lane & 15);
                af[mi] = *(const s16x8*)&As[r][((gb ^ r) & 7) * 8];
            }
#pragma unroll
            for (int ni = 0; ni < 4; ni++) {
                int r = wc * 64 + ni * 16 + (lane & 15);
                bf[ni] = *(const s16x8*)&Bs[r][((gb ^ r) & 7) * 8];
            }
#pragma unroll
            for (int mi = 0; mi < 4; mi++)
#pragma unroll
                for (int ni = 0; ni < 4; ni++) {
                    if (DT == 0)
                        acc[mi][ni] = __builtin_amdgcn_mfma_f32_16x16x32_f16(
                            __builtin_bit_cast(f16x8, af[mi]), __builtin_bit_cast(f16x8, bf[ni]),
                            acc[mi][ni], 0, 0, 0);
                    else
                        acc[mi][ni] = __builtin_amdgcn_mfma_f32_16x16x32_bf16(
                            __builtin_bit_cast(bf16x8, af[mi]), __builtin_bit_cast(bf16x8, bf[ni]),
                            acc[mi][ni], 0, 0, 0);
                }
        }
        __syncthreads();
    }
#pragma unroll
    for (int ni = 0; ni < 4; ni++) {
        int col = n0 + wc * 64 + ni * 16 + (lane & 15);
        float bv = bias[col];
#pragma unroll
        for (int mi = 0; mi < 4; mi++) {
            int rb = m0 + wr * 64 + mi * 16 + (lane >> 4) * 4;
#pragma unroll
            for (int j = 0; j < 4; j++) {
                float x = acc[mi][ni][j];
                if (DT == 0) {
                    x = x * (1.0f / 256.0f) + bv;
                    ((float*)Out)[(size_t)(rb + j) * N + col] = x > 0.f ? x : 0.f;
                } else if (DT == 1) {
                    x += bv;
                    ((u16*)Out)[(size_t)(rb + j) * N + col] = f2bf_rn(x > 0.f ? x : 0.f);
                } else {
                    x += bv;
                    ((float*)Out)[(size_t)(rb + j) * N + col] = 1.f / (1.f + __expf(-x));
                }
            }
        }
    }
}

// ---------------- top-64 of 1024 per row: threshold via bit binary search ----------------
__global__ __launch_bounds__(256) void topk_kernel(const float* __restrict__ H,
                                                   u16* __restrict__ HM,
                                                   float* __restrict__ rowT,
                                                   unsigned* __restrict__ rowFlag) {
    int row = blockIdx.x * 4 + (threadIdx.x >> 6);
    int lane = threadIdx.x & 63;
    const float* hr = H + (size_t)row * 1024;
    float v[16];
#pragma unroll
    for (int i = 0; i < 4; i++) *(f32x4*)&v[i * 4] = *(const f32x4*)(hr + lane * 16 + i * 4);
    unsigned u[16];
#pragma unroll
    for (int i = 0; i < 16; i++) u[i] = __float_as_uint(v[i]);
    unsigned lo = 0;
    for (int b = 30; b >= 0; --b) {
        unsigned cand = lo | (1u << b);
        int c = 0;
#pragma unroll
        for (int i = 0; i < 16; i++) c += (u[i] >= cand);
#pragma unroll
        for (int off = 32; off; off >>= 1) c += __shfl_xor(c, off);
        if (c >= 64) lo = cand;
    }
    unsigned m2 = 0;
#pragma unroll
    for (int i = 0; i < 16; i++)
        if (u[i] < lo && u[i] > m2) m2 = u[i];
#pragma unroll
    for (int off = 32; off; off >>= 1) {
        unsigned o = __shfl_xor(m2, off);
        if (o > m2) m2 = o;
    }
    u16 o16[16];
#pragma unroll
    for (int i = 0; i < 16; i++) o16[i] = (u[i] >= lo) ? f2bf_rn(v[i]) : (u16)0;
    unsigned p[8];
#pragma unroll
    for (int i = 0; i < 8; i++) p[i] = (unsigned)o16[2 * i] | ((unsigned)o16[2 * i + 1] << 16);
    u16* dst = HM + (size_t)row * 1024 + lane * 16;
    *(uint4*)dst = make_uint4(p[0], p[1], p[2], p[3]);
    *(uint4*)(dst + 8) = make_uint4(p[4], p[5], p[6], p[7]);
    if (lane == 0) {
        rowT[row] = __uint_as_float(lo);
        float t = __uint_as_float(lo), s = __uint_as_float(m2);
        rowFlag[row] = (lo != 0u) && (t - s < SEL_BAND);
    }
}

// ---------------- fp64 fix-up: 256 thr, wave-per-candidate, 4-chain dots ----------------
__global__ __launch_bounds__(256) void fixup_kernel(const float* __restrict__ H,
                                                    const float* __restrict__ X,
                                                    const float* __restrict__ W,  // [1024][12288] f32 (We1^T)
                                                    const float* __restrict__ be1,
                                                    const float* __restrict__ rowT,
                                                    const unsigned* __restrict__ rowFlag,
                                                    u16* __restrict__ HM) {
    int row = blockIdx.x;
    if (!rowFlag[row]) return;
    int tid = threadIdx.x, lane = tid & 63, wv = tid >> 6;
    float Tf = rowT[row];
    const float* hr = H + (size_t)row * 1024;
    f32x4 v = *(const f32x4*)(hr + tid * 4);
    __shared__ int bidx[64];
    __shared__ float bval[64];
    __shared__ double dval[64];
    __shared__ int cnt, csh;
    if (tid == 0) { cnt = 0; csh = 0; }
    __syncthreads();
    int myS = 0;
#pragma unroll
    for (int i = 0; i < 4; i++) {
        float x = v[i];
        if (fabsf(x - Tf) <= SEL_BAND) {
            int p = atomicAdd(&cnt, 1);
            if (p < 64) { bidx[p] = tid * 4 + i; bval[p] = x; }
        }
        myS += (x > Tf + SEL_BAND);
    }
#pragma unroll
    for (int off = 32; off; off >>= 1) myS += __shfl_xor(myS, off);
    if (lane == 0) atomicAdd(&csh, myS);
    __syncthreads();
    int nb = cnt < 64 ? cnt : 64;
    if (nb < 2) return;
    int kband = 64 - csh;
    const float* xr = X + (size_t)row * 12288;
    for (int e = wv; e < nb; e += 4) {
        const float* wp = W + (size_t)bidx[e] * 12288;
        double s0 = 0, s1 = 0, s2 = 0, s3 = 0;
        for (int k0 = 0; k0 < 12288; k0 += 256) {
            s0 += (double)xr[k0 + lane]       * (double)wp[k0 + lane];
            s1 += (double)xr[k0 + 64 + lane]  * (double)wp[k0 + 64 + lane];
            s2 += (double)xr[k0 + 128 + lane] * (double)wp[k0 + 128 + lane];
            s3 += (double)xr[k0 + 192 + lane] * (double)wp[k0 + 192 + lane];
        }
        double s = (s0 + s1) + (s2 + s3);
#pragma unroll
        for (int off = 32; off; off >>= 1) s += __shfl_xor(s, off);
        if (lane == 0) dval[e] = s + (double)be1[bidx[e]];
    }
    __syncthreads();
    if (tid < nb) {
        double me = dval[tid];
        int j = bidx[tid];
        int rank = 0;
        for (int f = 0; f < nb; f++) {
            double df = dval[f];
            rank += (df > me) || (df == me && bidx[f] < j);
        }
        HM[(size_t)row * 1024 + j] = (rank < kband) ? f2bf_rn(bval[tid]) : (u16)0;
    }
}

extern "C" void kernel_launch(void* const* d_in, const int* in_sizes, int n_in,
                              void* d_out, int out_size, void* d_ws, size_t ws_size,
                              hipStream_t stream) {
    const float* X   = (const float*)d_in[0];
    const float* We1 = (const float*)d_in[1];
    const float* be1 = (const float*)d_in[2];
    const float* Wd1 = (const float*)d_in[3];
    const float* bd1 = (const float*)d_in[4];
    const float* Wd2 = (const float*)d_in[5];
    const float* bd2 = (const float*)d_in[6];

    char* ws = (char*)d_ws;
    size_t off = 0;
    auto alloc = [&](size_t bytes) { void* p = ws + off; off += (bytes + 255) & ~(size_t)255; return p; };

    const size_t PREF_NEED = 190ull << 20;   // preferred layout ~187 MB
    dim3 tb(32, 8);

    if (ws_size >= PREF_NEED) {
        u16* Xh     = (u16*)alloc(4096ull * 12288 * 2);   // 100.7 MB; reused as We1Tf after gemm1
        u16* W1hT   = (u16*)alloc(12288ull * 1024 * 2);
        u16* Wd1T   = (u16*)alloc(1024ull * 1024 * 2);
        u16* Wd2T   = (u16*)alloc(1024ull * 12288 * 2);
        float* Hbuf = (float*)alloc(4096ull * 1024 * 4);
        u16* HM     = (u16*)alloc(4096ull * 1024 * 2);
        u16* Dbf    = (u16*)alloc(4096ull * 1024 * 2);
        float* rowT = (float*)alloc(4096 * 4);
        unsigned* rowFlag = (unsigned*)alloc(4096 * 4);
        float* We1Tf = (float*)Xh;                        // alias: live only after gemm1

        xcvt<<<2048, 256, 0, stream>>>(X, Xh, 4096 * 12288 / 8);
        tr_h<<<dim3(32, 384), tb, 0, stream>>>(We1, 12288, 1024, W1hT);
        tr_bf16<<<dim3(32, 32), tb, 0, stream>>>(Wd1, 1024, 1024, Wd1T);
        tr_bf16<<<dim3(384, 32), tb, 0, stream>>>(Wd2, 1024, 12288, Wd2T);

        gemm_t<0, false><<<dim3(32, 8), 256, 0, stream>>>(Xh, W1hT, be1, Hbuf, 4096, 1024, 12288);
        tr_f32<<<dim3(32, 384), tb, 0, stream>>>(We1, 12288, 1024, We1Tf);
        topk_kernel<<<1024, 256, 0, stream>>>(Hbuf, HM, rowT, rowFlag);
        fixup_kernel<<<4096, 256, 0, stream>>>(Hbuf, X, We1Tf, be1, rowT, rowFlag, HM);
        gemm_t<1, false><<<dim3(32, 8), 256, 0, stream>>>(HM, Wd1T, bd1, Dbf, 4096, 1024, 1024);
        gemm_t<2, false><<<dim3(32, 96), 256, 0, stream>>>(Dbf, Wd2T, bd2, d_out, 4096, 12288, 1024);
    } else {
        u16* W1hT    = (u16*)alloc(12288ull * 1024 * 2);
        float* We1Tf = (float*)alloc(12288ull * 1024 * 4);
        u16* Wd1T    = (u16*)alloc(1024ull * 1024 * 2);
        u16* Wd2T    = (u16*)alloc(1024ull * 12288 * 2);
        float* Hbuf  = (float*)alloc(4096ull * 1024 * 4);
        u16* HM      = (u16*)alloc(4096ull * 1024 * 2);
        u16* Dbf     = (u16*)alloc(4096ull * 1024 * 2);
        float* rowT  = (float*)alloc(4096 * 4);
        unsigned* rowFlag = (unsigned*)alloc(4096 * 4);

        tr_hf<<<dim3(32, 384), tb, 0, stream>>>(We1, 12288, 1024, W1hT, We1Tf);
        tr_bf16<<<dim3(32, 32), tb, 0, stream>>>(Wd1, 1024, 1024, Wd1T);
        tr_bf16<<<dim3(384, 32), tb, 0, stream>>>(Wd2, 1024, 12288, Wd2T);

        gemm_t<0, true><<<dim3(32, 8), 256, 0, stream>>>(X, W1hT, be1, Hbuf, 4096, 1024, 12288);
        topk_kernel<<<1024, 256, 0, stream>>>(Hbuf, HM, rowT, rowFlag);
        fixup_kernel<<<4096, 256, 0, stream>>>(Hbuf, X, We1Tf, be1, rowT, rowFlag, HM);
        gemm_t<1, false><<<dim3(32, 8), 256, 0, stream>>>(HM, Wd1T, bd1, Dbf, 4096, 1024, 1024);
        gemm_t<2, false><<<dim3(32, 96), 256, 0, stream>>>(Dbf, Wd2T, bd2, d_out, 4096, 12288, 1024);
    }
}

// Round 6
// 706.845 us; speedup vs baseline: 1.0559x; 1.0559x over previous
//
#include <hip/hip_runtime.h>

typedef float f32x4 __attribute__((ext_vector_type(4)));
typedef __bf16 bf16x8 __attribute__((ext_vector_type(8)));
typedef _Float16 f16x8 __attribute__((ext_vector_type(8)));
typedef short s16x8 __attribute__((ext_vector_type(8)));
typedef unsigned short u16;

#define DEV static __device__ __forceinline__

#define SEL_BAND 2.0e-3f   // fp16-GEMM1 error band for exact re-ranking

DEV u16 f2bf_rn(float f) {
    unsigned u = __float_as_uint(f);
    return (u16)((u + 0x7fffu + ((u >> 16) & 1u)) >> 16);
}

typedef __attribute__((address_space(3))) unsigned int lds_u32;
typedef __attribute__((address_space(1))) const unsigned int glb_u32;

DEV void gload16(const void* g, void* l) {
    __builtin_amdgcn_global_load_lds((glb_u32*)g, (lds_u32*)l, 16, 0, 0);
}

// ---------------- transpose [R][C] f32 -> [C][R] fp16*256 + f32 ----------------
__global__ __launch_bounds__(256) void tr_hf(const float* __restrict__ src, int R, int C,
                                             u16* __restrict__ hT, float* __restrict__ fT) {
    __shared__ float t[32][33];
    int tx = threadIdx.x, ty = threadIdx.y;
    int c0 = blockIdx.x * 32, r0 = blockIdx.y * 32;
#pragma unroll
    for (int i = 0; i < 4; i++) t[ty + i * 8][tx] = src[(size_t)(r0 + ty + i * 8) * C + c0 + tx];
    __syncthreads();
#pragma unroll
    for (int i = 0; i < 4; i++) {
        int c = c0 + ty + i * 8;
        float v = t[tx][ty + i * 8];
        size_t o = (size_t)c * R + r0 + tx;
        hT[o] = __builtin_bit_cast(u16, (_Float16)(v * 256.0f));
        fT[o] = v;
    }
}

// ---------------- transpose [R][C] f32 -> [C][R] bf16 ----------------
__global__ __launch_bounds__(256) void tr_bf16(const float* __restrict__ src, int R, int C,
                                               u16* __restrict__ dst) {
    __shared__ float t[32][33];
    int tx = threadIdx.x, ty = threadIdx.y;
    int c0 = blockIdx.x * 32, r0 = blockIdx.y * 32;
#pragma unroll
    for (int i = 0; i < 4; i++) t[ty + i * 8][tx] = src[(size_t)(r0 + ty + i * 8) * C + c0 + tx];
    __syncthreads();
#pragma unroll
    for (int i = 0; i < 4; i++)
        dst[(size_t)(c0 + ty + i * 8) * R + r0 + tx] = f2bf_rn(t[tx][ty + i * 8]);
}

// ---------------- m97-structure GEMM, optional split-K ----------------
// DT 0: f16 MFMA, epi = acc/256 + bias, relu -> f32         (gemm1, SPLITK=1)
// DT 1: bf16 MFMA, epi = relu -> bf16                       (gemm2)
// DT 2: bf16 MFMA, epi = sigmoid -> f32                     (gemm3)
// DT 3: f16 MFMA, epi = acc/256 raw -> f32 partial [z][M][N] (gemm1 split-K)
// AF32: A source f32, reg-staged cvt->f16 into swizzled LDS.
template <int BM, int BN, int DT, int SPLITK, bool AF32>
__global__ __launch_bounds__(256, 4) void gemm_t(const void* __restrict__ Ap,
                                                 const u16* __restrict__ BT,
                                                 const float* __restrict__ bias,
                                                 void* __restrict__ Out,
                                                 int M, int N, int K) {
    constexpr int WM = BM / 2, WN = BN / 2, MI = WM / 16, NI = WN / 16;
    constexpr bool F16 = (DT == 0 || DT == 3);
    __shared__ __align__(16) u16 As[BM][64];
    __shared__ __align__(16) u16 Bs[BN][64];
    int tid = threadIdx.x, lane = tid & 63, wid = tid >> 6;
    int wr = wid >> 1, wc = wid & 1;

    // bijective XCD swizzle over the whole grid (nwg % 8 == 0 for all our grids)
    int lin = blockIdx.x + gridDim.x * (blockIdx.y + gridDim.y * blockIdx.z);
    int nwg = gridDim.x * gridDim.y * gridDim.z;
    int q = nwg >> 3;
    int logical = (lin & 7) * q + (lin >> 3);
    int Ny = N / BN;
    int per = (M / BM) * Ny;
    int z = logical / per;
    int rem = logical - z * per;
    int mb = rem / Ny, nb = rem - mb * Ny;
    int m0 = mb * BM, n0 = nb * BN;
    int Ksl = K / SPLITK;
    int kbase = z * Ksl;

    f32x4 acc[MI][NI] = {};
    int NT = Ksl >> 6;
    for (int t = 0; t < NT; ++t) {
        int k0 = kbase + (t << 6);
        if (AF32) {
            const float* Af = (const float*)Ap;
#pragma unroll
            for (int i = 0; i < BM / 16; i++) {
                int s = i * 256 + tid;
                int r = s >> 4, qd = s & 15;
                f32x4 v = *(const f32x4*)(Af + (size_t)(m0 + r) * K + k0 + qd * 4);
                u16 h[4];
#pragma unroll
                for (int j = 0; j < 4; j++) h[j] = __builtin_bit_cast(u16, (_Float16)v[j]);
                int g = qd >> 1;
                int dst = ((g ^ r) & 7) * 16 + (qd & 1) * 8;
                *(uint2*)((char*)&As[r][0] + dst) =
                    make_uint2((unsigned)h[0] | ((unsigned)h[1] << 16),
                               (unsigned)h[2] | ((unsigned)h[3] << 16));
            }
        } else {
            const u16* Au = (const u16*)Ap;
#pragma unroll
            for (int i = 0; i < BM / 32; i++) {
                int s = i * 256 + tid;
                int r = s >> 3, g = s & 7;
                int gs = (g ^ r) & 7;
                gload16(Au + (size_t)(m0 + r) * K + k0 + gs * 8, &As[r][g * 8]);
            }
        }
#pragma unroll
        for (int i = 0; i < BN / 32; i++) {
            int s = i * 256 + tid;
            int r = s >> 3, g = s & 7;
            int gs = (g ^ r) & 7;
            gload16(BT + (size_t)(n0 + r) * K + k0 + gs * 8, &Bs[r][g * 8]);
        }
        __syncthreads();
#pragma unroll
        for (int kk = 0; kk < 2; kk++) {
            int gb = kk * 4 + (lane >> 4);   // K-granule index 0..7
            s16x8 af[MI], bf[NI];
#pragma unroll
            for (int mi = 0; mi < MI; mi++) {
                int r = wr * WM + mi * 16 + (lane & 15);
                af[mi] = *(const s16x8*)&As[r][((gb ^ r) & 7) * 8];
            }
#pragma unroll
            for (int ni = 0; ni < NI; ni++) {
                int r = wc * WN + ni * 16 + (lane & 15);
                bf[ni] = *(const s16x8*)&Bs[r][((gb ^ r) & 7) * 8];
            }
#pragma unroll
            for (int mi = 0; mi < MI; mi++)
#pragma unroll
                for (int ni = 0; ni < NI; ni++) {
                    if (F16)
                        acc[mi][ni] = __builtin_amdgcn_mfma_f32_16x16x32_f16(
                            __builtin_bit_cast(f16x8, af[mi]), __builtin_bit_cast(f16x8, bf[ni]),
                            acc[mi][ni], 0, 0, 0);
                    else
                        acc[mi][ni] = __builtin_amdgcn_mfma_f32_16x16x32_bf16(
                            __builtin_bit_cast(bf16x8, af[mi]), __builtin_bit_cast(bf16x8, bf[ni]),
                            acc[mi][ni], 0, 0, 0);
                }
        }
        __syncthreads();
    }
    float* Outz = (DT == 3) ? (float*)Out + (size_t)z * M * N : (float*)Out;
#pragma unroll
    for (int ni = 0; ni < NI; ni++) {
        int col = n0 + wc * WN + ni * 16 + (lane & 15);
        float bv = (DT == 3) ? 0.f : bias[col];
#pragma unroll
        for (int mi = 0; mi < MI; mi++) {
            int rb = m0 + wr * WM + mi * 16 + (lane >> 4) * 4;
#pragma unroll
            for (int j = 0; j < 4; j++) {
                float x = acc[mi][ni][j];
                if (DT == 3) {
                    Outz[(size_t)(rb + j) * N + col] = x * (1.0f / 256.0f);
                } else if (DT == 0) {
                    x = x * (1.0f / 256.0f) + bv;
                    ((float*)Out)[(size_t)(rb + j) * N + col] = x > 0.f ? x : 0.f;
                } else if (DT == 1) {
                    x += bv;
                    ((u16*)Out)[(size_t)(rb + j) * N + col] = f2bf_rn(x > 0.f ? x : 0.f);
                } else {
                    x += bv;
                    ((float*)Out)[(size_t)(rb + j) * N + col] = 1.f / (1.f + __expf(-x));
                }
            }
        }
    }
}

// ---------------- split-K reduce: H = relu(sum_z P[z] + bias), in-place on P[0] ----------------
__global__ __launch_bounds__(256) void reduce_k(float* __restrict__ P, const float* __restrict__ bias,
                                                int total4, int nz, int colmask4) {
    int i = blockIdx.x * 256 + threadIdx.x;
    int stride = gridDim.x * 256;
    for (; i < total4; i += stride) {
        f32x4 a = ((const f32x4*)P)[i];
        for (int zz = 1; zz < nz; zz++) a += ((const f32x4*)P)[i + (size_t)zz * total4];
        f32x4 b = ((const f32x4*)bias)[i & colmask4];
        a += b;
#pragma unroll
        for (int j = 0; j < 4; j++) a[j] = a[j] > 0.f ? a[j] : 0.f;
        ((f32x4*)P)[i] = a;
    }
}

// ---------------- top-64 of 1024 per row: threshold via bit binary search ----------------
__global__ __launch_bounds__(256) void topk_kernel(const float* __restrict__ H,
                                                   u16* __restrict__ HM,
                                                   float* __restrict__ rowT,
                                                   unsigned* __restrict__ rowFlag) {
    int row = blockIdx.x * 4 + (threadIdx.x >> 6);
    int lane = threadIdx.x & 63;
    const float* hr = H + (size_t)row * 1024;
    float v[16];
#pragma unroll
    for (int i = 0; i < 4; i++) *(f32x4*)&v[i * 4] = *(const f32x4*)(hr + lane * 16 + i * 4);
    unsigned u[16];
#pragma unroll
    for (int i = 0; i < 16; i++) u[i] = __float_as_uint(v[i]);
    unsigned lo = 0;
    for (int b = 30; b >= 0; --b) {
        unsigned cand = lo | (1u << b);
        int c = 0;
#pragma unroll
        for (int i = 0; i < 16; i++) c += (u[i] >= cand);
#pragma unroll
        for (int off = 32; off; off >>= 1) c += __shfl_xor(c, off);
        if (c >= 64) lo = cand;
    }
    unsigned m2 = 0;
#pragma unroll
    for (int i = 0; i < 16; i++)
        if (u[i] < lo && u[i] > m2) m2 = u[i];
#pragma unroll
    for (int off = 32; off; off >>= 1) {
        unsigned o = __shfl_xor(m2, off);
        if (o > m2) m2 = o;
    }
    u16 o16[16];
#pragma unroll
    for (int i = 0; i < 16; i++) o16[i] = (u[i] >= lo) ? f2bf_rn(v[i]) : (u16)0;
    unsigned p[8];
#pragma unroll
    for (int i = 0; i < 8; i++) p[i] = (unsigned)o16[2 * i] | ((unsigned)o16[2 * i + 1] << 16);
    u16* dst = HM + (size_t)row * 1024 + lane * 16;
    *(uint4*)dst = make_uint4(p[0], p[1], p[2], p[3]);
    *(uint4*)(dst + 8) = make_uint4(p[4], p[5], p[6], p[7]);
    if (lane == 0) {
        rowT[row] = __uint_as_float(lo);
        float t = __uint_as_float(lo), s = __uint_as_float(m2);
        rowFlag[row] = (lo != 0u) && (t - s < SEL_BAND);
    }
}

// ---------------- fp64 fix-up: 256 thr, wave-per-candidate, 4-chain dots ----------------
__global__ __launch_bounds__(256) void fixup_kernel(const float* __restrict__ H,
                                                    const float* __restrict__ X,
                                                    const float* __restrict__ W,  // [1024][12288] f32 (We1^T)
                                                    const float* __restrict__ be1,
                                                    const float* __restrict__ rowT,
                                                    const unsigned* __restrict__ rowFlag,
                                                    u16* __restrict__ HM) {
    int row = blockIdx.x;
    if (!rowFlag[row]) return;
    int tid = threadIdx.x, lane = tid & 63, wv = tid >> 6;
    float Tf = rowT[row];
    const float* hr = H + (size_t)row * 1024;
    f32x4 v = *(const f32x4*)(hr + tid * 4);
    __shared__ int bidx[64];
    __shared__ float bval[64];
    __shared__ double dval[64];
    __shared__ int cnt, csh;
    if (tid == 0) { cnt = 0; csh = 0; }
    __syncthreads();
    int myS = 0;
#pragma unroll
    for (int i = 0; i < 4; i++) {
        float x = v[i];
        if (fabsf(x - Tf) <= SEL_BAND) {
            int p = atomicAdd(&cnt, 1);
            if (p < 64) { bidx[p] = tid * 4 + i; bval[p] = x; }
        }
        myS += (x > Tf + SEL_BAND);
    }
#pragma unroll
    for (int off = 32; off; off >>= 1) myS += __shfl_xor(myS, off);
    if (lane == 0) atomicAdd(&csh, myS);
    __syncthreads();
    int nb = cnt < 64 ? cnt : 64;
    if (nb < 2) return;
    int kband = 64 - csh;
    const float* xr = X + (size_t)row * 12288;
    for (int e = wv; e < nb; e += 4) {
        const float* wp = W + (size_t)bidx[e] * 12288;
        double s0 = 0, s1 = 0, s2 = 0, s3 = 0;
        for (int k0 = 0; k0 < 12288; k0 += 256) {
            s0 += (double)xr[k0 + lane]       * (double)wp[k0 + lane];
            s1 += (double)xr[k0 + 64 + lane]  * (double)wp[k0 + 64 + lane];
            s2 += (double)xr[k0 + 128 + lane] * (double)wp[k0 + 128 + lane];
            s3 += (double)xr[k0 + 192 + lane] * (double)wp[k0 + 192 + lane];
        }
        double s = (s0 + s1) + (s2 + s3);
#pragma unroll
        for (int off = 32; off; off >>= 1) s += __shfl_xor(s, off);
        if (lane == 0) dval[e] = s + (double)be1[bidx[e]];
    }
    __syncthreads();
    if (tid < nb) {
        double me = dval[tid];
        int j = bidx[tid];
        int rank = 0;
        for (int f = 0; f < nb; f++) {
            double df = dval[f];
            rank += (df > me) || (df == me && bidx[f] < j);
        }
        HM[(size_t)row * 1024 + j] = (rank < kband) ? f2bf_rn(bval[tid]) : (u16)0;
    }
}

extern "C" void kernel_launch(void* const* d_in, const int* in_sizes, int n_in,
                              void* d_out, int out_size, void* d_ws, size_t ws_size,
                              hipStream_t stream) {
    const float* X   = (const float*)d_in[0];
    const float* We1 = (const float*)d_in[1];
    const float* be1 = (const float*)d_in[2];
    const float* Wd1 = (const float*)d_in[3];
    const float* bd1 = (const float*)d_in[4];
    const float* Wd2 = (const float*)d_in[5];
    const float* bd2 = (const float*)d_in[6];

    // workspace tiers: base 136.3 MB (proven) + (SPLITK-1) x 16.8 MB partials
    int splitk = (ws_size >= 187100000ull) ? 4 : (ws_size >= 153600000ull) ? 2 : 1;

    char* ws = (char*)d_ws;
    size_t off = 0;
    auto alloc = [&](size_t bytes) { void* p = ws + off; off += (bytes + 255) & ~(size_t)255; return p; };
    u16* W1hT    = (u16*)alloc(12288ull * 1024 * 2);   // fp16 bits x256, [1024][12288]
    float* We1Tf = (float*)alloc(12288ull * 1024 * 4); // f32 [1024][12288] for fixup
    u16* Wd1T    = (u16*)alloc(1024ull * 1024 * 2);
    u16* Wd2T    = (u16*)alloc(1024ull * 12288 * 2);
    float* Hbuf  = (float*)alloc((size_t)splitk * 4096 * 1024 * 4);  // partial[0] == Hbuf
    u16* HM      = (u16*)alloc(4096ull * 1024 * 2);
    u16* Dbf     = (u16*)alloc(4096ull * 1024 * 2);
    float* rowT  = (float*)alloc(4096 * 4);
    unsigned* rowFlag = (unsigned*)alloc(4096 * 4);

    dim3 tb(32, 8);
    tr_hf<<<dim3(32, 384), tb, 0, stream>>>(We1, 12288, 1024, W1hT, We1Tf);
    tr_bf16<<<dim3(32, 32), tb, 0, stream>>>(Wd1, 1024, 1024, Wd1T);
    tr_bf16<<<dim3(384, 32), tb, 0, stream>>>(Wd2, 1024, 12288, Wd2T);

    if (splitk == 4) {
        gemm_t<128, 128, 3, 4, true><<<dim3(32, 8, 4), 256, 0, stream>>>(X, W1hT, be1, Hbuf, 4096, 1024, 12288);
        reduce_k<<<2048, 256, 0, stream>>>(Hbuf, be1, 4096 * 1024 / 4, 4, 255);
    } else if (splitk == 2) {
        gemm_t<128, 128, 3, 2, true><<<dim3(32, 8, 2), 256, 0, stream>>>(X, W1hT, be1, Hbuf, 4096, 1024, 12288);
        reduce_k<<<2048, 256, 0, stream>>>(Hbuf, be1, 4096 * 1024 / 4, 2, 255);
    } else {
        gemm_t<128, 128, 0, 1, true><<<dim3(32, 8), 256, 0, stream>>>(X, W1hT, be1, Hbuf, 4096, 1024, 12288);
    }
    topk_kernel<<<1024, 256, 0, stream>>>(Hbuf, HM, rowT, rowFlag);
    fixup_kernel<<<4096, 256, 0, stream>>>(Hbuf, X, We1Tf, be1, rowT, rowFlag, HM);
    gemm_t<64, 128, 1, 1, false><<<dim3(64, 8), 256, 0, stream>>>(HM, Wd1T, bd1, Dbf, 4096, 1024, 1024);
    gemm_t<128, 128, 2, 1, false><<<dim3(32, 96), 256, 0, stream>>>(Dbf, Wd2T, bd2, d_out, 4096, 12288, 1024);
}

// Round 7
// 664.531 us; speedup vs baseline: 1.1232x; 1.0637x over previous
//
#include <hip/hip_runtime.h>

typedef float f32x4 __attribute__((ext_vector_type(4)));
typedef __bf16 bf16x8 __attribute__((ext_vector_type(8)));
typedef _Float16 f16x8 __attribute__((ext_vector_type(8)));
typedef short s16x8 __attribute__((ext_vector_type(8)));
typedef unsigned short u16;

#define DEV static __device__ __forceinline__

#define SEL_BAND 2.0e-3f   // fp16-GEMM1 error band for exact re-ranking

DEV u16 f2bf_rn(float f) {
    unsigned u = __float_as_uint(f);
    return (u16)((u + 0x7fffu + ((u >> 16) & 1u)) >> 16);
}

typedef __attribute__((address_space(3))) unsigned int lds_u32;
typedef __attribute__((address_space(1))) const unsigned int glb_u32;

DEV void gload16(const void* g, void* l) {
    __builtin_amdgcn_global_load_lds((glb_u32*)g, (lds_u32*)l, 16, 0, 0);
}

// ---------------- transpose [R][C] f32 -> [C][R] fp16*256 + f32 ----------------
__global__ __launch_bounds__(256) void tr_hf(const float* __restrict__ src, int R, int C,
                                             u16* __restrict__ hT, float* __restrict__ fT) {
    __shared__ float t[32][33];
    int tx = threadIdx.x, ty = threadIdx.y;
    int c0 = blockIdx.x * 32, r0 = blockIdx.y * 32;
#pragma unroll
    for (int i = 0; i < 4; i++) t[ty + i * 8][tx] = src[(size_t)(r0 + ty + i * 8) * C + c0 + tx];
    __syncthreads();
#pragma unroll
    for (int i = 0; i < 4; i++) {
        int c = c0 + ty + i * 8;
        float v = t[tx][ty + i * 8];
        size_t o = (size_t)c * R + r0 + tx;
        hT[o] = __builtin_bit_cast(u16, (_Float16)(v * 256.0f));
        fT[o] = v;
    }
}

// ---------------- transpose [R][C] f32 -> [C][R] bf16 ----------------
__global__ __launch_bounds__(256) void tr_bf16(const float* __restrict__ src, int R, int C,
                                               u16* __restrict__ dst) {
    __shared__ float t[32][33];
    int tx = threadIdx.x, ty = threadIdx.y;
    int c0 = blockIdx.x * 32, r0 = blockIdx.y * 32;
#pragma unroll
    for (int i = 0; i < 4; i++) t[ty + i * 8][tx] = src[(size_t)(r0 + ty + i * 8) * C + c0 + tx];
    __syncthreads();
#pragma unroll
    for (int i = 0; i < 4; i++)
        dst[(size_t)(c0 + ty + i * 8) * R + r0 + tx] = f2bf_rn(t[tx][ty + i * 8]);
}

// ---------------- m97-structure GEMM, optional split-K ----------------
// DT 0: f16 MFMA, epi = acc/256 + bias, relu -> f32          (gemm1, SPLITK=1)
// DT 1: bf16 MFMA, epi = relu -> bf16                        (gemm2)
// DT 2: bf16 MFMA, epi = sigmoid -> f32                      (gemm3)
// DT 3: f16 MFMA, epi = acc/256 raw -> f32 partial [z][M][N] (gemm1 split-K)
// AF32: A source f32, reg-staged cvt->f16 into swizzled LDS.
// COLM: XCD chunk decode M-fastest (each XCD owns contiguous N-range -> B L2-resident).
template <int BM, int BN, int DT, int SPLITK, bool AF32, bool COLM>
__global__ __launch_bounds__(256) void gemm_t(const void* __restrict__ Ap,
                                              const u16* __restrict__ BT,
                                              const float* __restrict__ bias,
                                              void* __restrict__ Out,
                                              int M, int N, int K) {
    constexpr int WM = BM / 2, WN = BN / 2, MI = WM / 16, NI = WN / 16;
    constexpr bool F16 = (DT == 0 || DT == 3);
    __shared__ __align__(16) u16 As[BM][64];
    __shared__ __align__(16) u16 Bs[BN][64];
    int tid = threadIdx.x, lane = tid & 63, wid = tid >> 6;
    int wr = wid >> 1, wc = wid & 1;

    // bijective XCD swizzle over the whole grid (nwg % 8 == 0 for all our grids)
    int lin = blockIdx.x + gridDim.x * (blockIdx.y + gridDim.y * blockIdx.z);
    int nwg = gridDim.x * gridDim.y * gridDim.z;
    int q = nwg >> 3;
    int logical = (lin & 7) * q + (lin >> 3);
    int Ny = N / BN, Mx = M / BM;
    int per = Mx * Ny;
    int z = logical / per;
    int rem = logical - z * per;
    int mb, nb;
    if (COLM) { mb = rem % Mx; nb = rem / Mx; }
    else      { mb = rem / Ny; nb = rem - mb * Ny; }
    int m0 = mb * BM, n0 = nb * BN;
    int Ksl = K / SPLITK;
    int kbase = z * Ksl;

    f32x4 acc[MI][NI] = {};
    int NT = Ksl >> 6;
    for (int t = 0; t < NT; ++t) {
        int k0 = kbase + (t << 6);
        if (AF32) {
            const float* Af = (const float*)Ap;
#pragma unroll
            for (int i = 0; i < BM / 16; i++) {
                int s = i * 256 + tid;
                int r = s >> 4, qd = s & 15;
                f32x4 v = *(const f32x4*)(Af + (size_t)(m0 + r) * K + k0 + qd * 4);
                u16 h[4];
#pragma unroll
                for (int j = 0; j < 4; j++) h[j] = __builtin_bit_cast(u16, (_Float16)v[j]);
                int g = qd >> 1;
                int dst = ((g ^ r) & 7) * 16 + (qd & 1) * 8;
                *(uint2*)((char*)&As[r][0] + dst) =
                    make_uint2((unsigned)h[0] | ((unsigned)h[1] << 16),
                               (unsigned)h[2] | ((unsigned)h[3] << 16));
            }
        } else {
            const u16* Au = (const u16*)Ap;
#pragma unroll
            for (int i = 0; i < BM / 32; i++) {
                int s = i * 256 + tid;
                int r = s >> 3, g = s & 7;
                int gs = (g ^ r) & 7;
                gload16(Au + (size_t)(m0 + r) * K + k0 + gs * 8, &As[r][g * 8]);
            }
        }
#pragma unroll
        for (int i = 0; i < BN / 32; i++) {
            int s = i * 256 + tid;
            int r = s >> 3, g = s & 7;
            int gs = (g ^ r) & 7;
            gload16(BT + (size_t)(n0 + r) * K + k0 + gs * 8, &Bs[r][g * 8]);
        }
        __syncthreads();
#pragma unroll
        for (int kk = 0; kk < 2; kk++) {
            int gb = kk * 4 + (lane >> 4);   // K-granule index 0..7
            s16x8 af[MI], bf[NI];
#pragma unroll
            for (int mi = 0; mi < MI; mi++) {
                int r = wr * WM + mi * 16 + (lane & 15);
                af[mi] = *(const s16x8*)&As[r][((gb ^ r) & 7) * 8];
            }
#pragma unroll
            for (int ni = 0; ni < NI; ni++) {
                int r = wc * WN + ni * 16 + (lane & 15);
                bf[ni] = *(const s16x8*)&Bs[r][((gb ^ r) & 7) * 8];
            }
#pragma unroll
            for (int mi = 0; mi < MI; mi++)
#pragma unroll
                for (int ni = 0; ni < NI; ni++) {
                    if (F16)
                        acc[mi][ni] = __builtin_amdgcn_mfma_f32_16x16x32_f16(
                            __builtin_bit_cast(f16x8, af[mi]), __builtin_bit_cast(f16x8, bf[ni]),
                            acc[mi][ni], 0, 0, 0);
                    else
                        acc[mi][ni] = __builtin_amdgcn_mfma_f32_16x16x32_bf16(
                            __builtin_bit_cast(bf16x8, af[mi]), __builtin_bit_cast(bf16x8, bf[ni]),
                            acc[mi][ni], 0, 0, 0);
                }
        }
        __syncthreads();
    }
    float* Outz = (DT == 3) ? (float*)Out + (size_t)z * M * N : (float*)Out;
#pragma unroll
    for (int ni = 0; ni < NI; ni++) {
        int col = n0 + wc * WN + ni * 16 + (lane & 15);
        float bv = (DT == 3) ? 0.f : bias[col];
#pragma unroll
        for (int mi = 0; mi < MI; mi++) {
            int rb = m0 + wr * WM + mi * 16 + (lane >> 4) * 4;
#pragma unroll
            for (int j = 0; j < 4; j++) {
                float x = acc[mi][ni][j];
                if (DT == 3) {
                    Outz[(size_t)(rb + j) * N + col] = x * (1.0f / 256.0f);
                } else if (DT == 0) {
                    x = x * (1.0f / 256.0f) + bv;
                    ((float*)Out)[(size_t)(rb + j) * N + col] = x > 0.f ? x : 0.f;
                } else if (DT == 1) {
                    x += bv;
                    ((u16*)Out)[(size_t)(rb + j) * N + col] = f2bf_rn(x > 0.f ? x : 0.f);
                } else {
                    x += bv;
                    ((float*)Out)[(size_t)(rb + j) * N + col] = 1.f / (1.f + __expf(-x));
                }
            }
        }
    }
}

// ---------------- split-K reduce: H = relu(sum_z P[z] + bias), in-place on P[0] ----------------
__global__ __launch_bounds__(256) void reduce_k(float* __restrict__ P, const float* __restrict__ bias,
                                                int total4, int nz, int colmask4) {
    int i = blockIdx.x * 256 + threadIdx.x;
    int stride = gridDim.x * 256;
    for (; i < total4; i += stride) {
        f32x4 a = ((const f32x4*)P)[i];
        for (int zz = 1; zz < nz; zz++) a += ((const f32x4*)P)[i + (size_t)zz * total4];
        f32x4 b = ((const f32x4*)bias)[i & colmask4];
        a += b;
#pragma unroll
        for (int j = 0; j < 4; j++) a[j] = a[j] > 0.f ? a[j] : 0.f;
        ((f32x4*)P)[i] = a;
    }
}

// ---------------- top-64 of 1024 per row: threshold via bit binary search ----------------
__global__ __launch_bounds__(256) void topk_kernel(const float* __restrict__ H,
                                                   u16* __restrict__ HM,
                                                   float* __restrict__ rowT,
                                                   unsigned* __restrict__ rowFlag) {
    int row = blockIdx.x * 4 + (threadIdx.x >> 6);
    int lane = threadIdx.x & 63;
    const float* hr = H + (size_t)row * 1024;
    float v[16];
#pragma unroll
    for (int i = 0; i < 4; i++) *(f32x4*)&v[i * 4] = *(const f32x4*)(hr + lane * 16 + i * 4);
    unsigned u[16];
#pragma unroll
    for (int i = 0; i < 16; i++) u[i] = __float_as_uint(v[i]);
    unsigned lo = 0;
    for (int b = 30; b >= 0; --b) {
        unsigned cand = lo | (1u << b);
        int c = 0;
#pragma unroll
        for (int i = 0; i < 16; i++) c += (u[i] >= cand);
#pragma unroll
        for (int off = 32; off; off >>= 1) c += __shfl_xor(c, off);
        if (c >= 64) lo = cand;
    }
    unsigned m2 = 0;
#pragma unroll
    for (int i = 0; i < 16; i++)
        if (u[i] < lo && u[i] > m2) m2 = u[i];
#pragma unroll
    for (int off = 32; off; off >>= 1) {
        unsigned o = __shfl_xor(m2, off);
        if (o > m2) m2 = o;
    }
    u16 o16[16];
#pragma unroll
    for (int i = 0; i < 16; i++) o16[i] = (u[i] >= lo) ? f2bf_rn(v[i]) : (u16)0;
    unsigned p[8];
#pragma unroll
    for (int i = 0; i < 8; i++) p[i] = (unsigned)o16[2 * i] | ((unsigned)o16[2 * i + 1] << 16);
    u16* dst = HM + (size_t)row * 1024 + lane * 16;
    *(uint4*)dst = make_uint4(p[0], p[1], p[2], p[3]);
    *(uint4*)(dst + 8) = make_uint4(p[4], p[5], p[6], p[7]);
    if (lane == 0) {
        rowT[row] = __uint_as_float(lo);
        float t = __uint_as_float(lo), s = __uint_as_float(m2);
        rowFlag[row] = (lo != 0u) && (t - s < SEL_BAND);
    }
}

// ---------------- fp64 fix-up: 256 thr, wave-per-candidate, 4-chain dots ----------------
__global__ __launch_bounds__(256) void fixup_kernel(const float* __restrict__ H,
                                                    const float* __restrict__ X,
                                                    const float* __restrict__ W,  // [1024][12288] f32 (We1^T)
                                                    const float* __restrict__ be1,
                                                    const float* __restrict__ rowT,
                                                    const unsigned* __restrict__ rowFlag,
                                                    u16* __restrict__ HM) {
    int row = blockIdx.x;
    if (!rowFlag[row]) return;
    int tid = threadIdx.x, lane = tid & 63, wv = tid >> 6;
    float Tf = rowT[row];
    const float* hr = H + (size_t)row * 1024;
    f32x4 v = *(const f32x4*)(hr + tid * 4);
    __shared__ int bidx[64];
    __shared__ float bval[64];
    __shared__ double dval[64];
    __shared__ int cnt, csh;
    if (tid == 0) { cnt = 0; csh = 0; }
    __syncthreads();
    int myS = 0;
#pragma unroll
    for (int i = 0; i < 4; i++) {
        float x = v[i];
        if (fabsf(x - Tf) <= SEL_BAND) {
            int p = atomicAdd(&cnt, 1);
            if (p < 64) { bidx[p] = tid * 4 + i; bval[p] = x; }
        }
        myS += (x > Tf + SEL_BAND);
    }
#pragma unroll
    for (int off = 32; off; off >>= 1) myS += __shfl_xor(myS, off);
    if (lane == 0) atomicAdd(&csh, myS);
    __syncthreads();
    int nb = cnt < 64 ? cnt : 64;
    if (nb < 2) return;
    int kband = 64 - csh;
    const float* xr = X + (size_t)row * 12288;
    for (int e = wv; e < nb; e += 4) {
        const float* wp = W + (size_t)bidx[e] * 12288;
        double s0 = 0, s1 = 0, s2 = 0, s3 = 0;
        for (int k0 = 0; k0 < 12288; k0 += 256) {
            s0 += (double)xr[k0 + lane]       * (double)wp[k0 + lane];
            s1 += (double)xr[k0 + 64 + lane]  * (double)wp[k0 + 64 + lane];
            s2 += (double)xr[k0 + 128 + lane] * (double)wp[k0 + 128 + lane];
            s3 += (double)xr[k0 + 192 + lane] * (double)wp[k0 + 192 + lane];
        }
        double s = (s0 + s1) + (s2 + s3);
#pragma unroll
        for (int off = 32; off; off >>= 1) s += __shfl_xor(s, off);
        if (lane == 0) dval[e] = s + (double)be1[bidx[e]];
    }
    __syncthreads();
    if (tid < nb) {
        double me = dval[tid];
        int j = bidx[tid];
        int rank = 0;
        for (int f = 0; f < nb; f++) {
            double df = dval[f];
            rank += (df > me) || (df == me && bidx[f] < j);
        }
        HM[(size_t)row * 1024 + j] = (rank < kband) ? f2bf_rn(bval[tid]) : (u16)0;
    }
}

extern "C" void kernel_launch(void* const* d_in, const int* in_sizes, int n_in,
                              void* d_out, int out_size, void* d_ws, size_t ws_size,
                              hipStream_t stream) {
    const float* X   = (const float*)d_in[0];
    const float* We1 = (const float*)d_in[1];
    const float* be1 = (const float*)d_in[2];
    const float* Wd1 = (const float*)d_in[3];
    const float* bd1 = (const float*)d_in[4];
    const float* Wd2 = (const float*)d_in[5];
    const float* bd2 = (const float*)d_in[6];

    // workspace tiers: base 136.3 MB (proven) + (SPLITK-1) x 16.8 MB partials
    int splitk = (ws_size >= 187100000ull) ? 4 : (ws_size >= 153600000ull) ? 2 : 1;

    char* ws = (char*)d_ws;
    size_t off = 0;
    auto alloc = [&](size_t bytes) { void* p = ws + off; off += (bytes + 255) & ~(size_t)255; return p; };
    u16* W1hT    = (u16*)alloc(12288ull * 1024 * 2);   // fp16 bits x256, [1024][12288]
    float* We1Tf = (float*)alloc(12288ull * 1024 * 4); // f32 [1024][12288] for fixup
    u16* Wd1T    = (u16*)alloc(1024ull * 1024 * 2);
    u16* Wd2T    = (u16*)alloc(1024ull * 12288 * 2);
    float* Hbuf  = (float*)alloc((size_t)splitk * 4096 * 1024 * 4);  // partial[0] == Hbuf
    u16* HM      = (u16*)alloc(4096ull * 1024 * 2);
    u16* Dbf     = (u16*)alloc(4096ull * 1024 * 2);
    float* rowT  = (float*)alloc(4096 * 4);
    unsigned* rowFlag = (unsigned*)alloc(4096 * 4);

    dim3 tb(32, 8);
    tr_hf<<<dim3(32, 384), tb, 0, stream>>>(We1, 12288, 1024, W1hT, We1Tf);
    tr_bf16<<<dim3(32, 32), tb, 0, stream>>>(Wd1, 1024, 1024, Wd1T);
    tr_bf16<<<dim3(384, 32), tb, 0, stream>>>(Wd2, 1024, 12288, Wd2T);

    if (splitk == 4) {
        gemm_t<128, 128, 3, 4, true, false><<<dim3(32, 8, 4), 256, 0, stream>>>(X, W1hT, be1, Hbuf, 4096, 1024, 12288);
        reduce_k<<<2048, 256, 0, stream>>>(Hbuf, be1, 4096 * 1024 / 4, 4, 255);
    } else if (splitk == 2) {
        gemm_t<128, 128, 3, 2, true, false><<<dim3(32, 8, 2), 256, 0, stream>>>(X, W1hT, be1, Hbuf, 4096, 1024, 12288);
        reduce_k<<<2048, 256, 0, stream>>>(Hbuf, be1, 4096 * 1024 / 4, 2, 255);
    } else {
        gemm_t<128, 128, 0, 1, true, false><<<dim3(32, 8), 256, 0, stream>>>(X, W1hT, be1, Hbuf, 4096, 1024, 12288);
    }
    topk_kernel<<<1024, 256, 0, stream>>>(Hbuf, HM, rowT, rowFlag);
    fixup_kernel<<<4096, 256, 0, stream>>>(Hbuf, X, We1Tf, be1, rowT, rowFlag, HM);
    gemm_t<64, 128, 1, 1, false, false><<<dim3(64, 8), 256, 0, stream>>>(HM, Wd1T, bd1, Dbf, 4096, 1024, 1024);
    gemm_t<128, 128, 2, 1, false, true><<<dim3(32, 96), 256, 0, stream>>>(Dbf, Wd2T, bd2, d_out, 4096, 12288, 1024);
}

// Round 8
// 600.124 us; speedup vs baseline: 1.2437x; 1.1073x over previous
//
#include <hip/hip_runtime.h>

typedef float f32x4 __attribute__((ext_vector_type(4)));
typedef __bf16 bf16x8 __attribute__((ext_vector_type(8)));
typedef _Float16 f16x8 __attribute__((ext_vector_type(8)));
typedef short s16x8 __attribute__((ext_vector_type(8)));
typedef unsigned short u16;

#define DEV static __device__ __forceinline__

#define SEL_BAND 2.0e-3f   // fp16-GEMM1 error band for exact re-ranking

DEV u16 f2bf_rn(float f) {
    unsigned u = __float_as_uint(f);
    return (u16)((u + 0x7fffu + ((u >> 16) & 1u)) >> 16);
}

typedef __attribute__((address_space(3))) unsigned int lds_u32;
typedef __attribute__((address_space(1))) const unsigned int glb_u32;

DEV void gload16(const void* g, void* l) {
    __builtin_amdgcn_global_load_lds((glb_u32*)g, (lds_u32*)l, 16, 0, 0);
}

// ---------------- transpose [R][C] f32 -> [C][R] fp16*256 + f32 ----------------
__global__ __launch_bounds__(256) void tr_hf(const float* __restrict__ src, int R, int C,
                                             u16* __restrict__ hT, float* __restrict__ fT) {
    __shared__ float t[32][33];
    int tx = threadIdx.x, ty = threadIdx.y;
    int c0 = blockIdx.x * 32, r0 = blockIdx.y * 32;
#pragma unroll
    for (int i = 0; i < 4; i++) t[ty + i * 8][tx] = src[(size_t)(r0 + ty + i * 8) * C + c0 + tx];
    __syncthreads();
#pragma unroll
    for (int i = 0; i < 4; i++) {
        int c = c0 + ty + i * 8;
        float v = t[tx][ty + i * 8];
        size_t o = (size_t)c * R + r0 + tx;
        hT[o] = __builtin_bit_cast(u16, (_Float16)(v * 256.0f));
        fT[o] = v;
    }
}

// ---------------- transpose [R][C] f32 -> [C][R] bf16 ----------------
__global__ __launch_bounds__(256) void tr_bf16(const float* __restrict__ src, int R, int C,
                                               u16* __restrict__ dst) {
    __shared__ float t[32][33];
    int tx = threadIdx.x, ty = threadIdx.y;
    int c0 = blockIdx.x * 32, r0 = blockIdx.y * 32;
#pragma unroll
    for (int i = 0; i < 4; i++) t[ty + i * 8][tx] = src[(size_t)(r0 + ty + i * 8) * C + c0 + tx];
    __syncthreads();
#pragma unroll
    for (int i = 0; i < 4; i++)
        dst[(size_t)(c0 + ty + i * 8) * R + r0 + tx] = f2bf_rn(t[tx][ty + i * 8]);
}

// ---------------- m97-structure GEMM, optional split-K ----------------
// DT 0: f16 MFMA, epi = acc/256 + bias, relu -> f32          (gemm1, SPLITK=1)
// DT 1: bf16 MFMA, epi = relu -> bf16                        (gemm2)
// DT 2: bf16 MFMA, epi = sigmoid -> f32 nt-store             (gemm3)
// DT 3: f16 MFMA, epi = acc/256 raw -> f32 partial, nt-store (gemm1 split-K)
// AF32: A source f32, reg-staged cvt->f16 into swizzled LDS.
// CM=0: N-major decode (with z). CM>0: chunked decode — each XCD owns CM
//       contiguous M-blocks x all N, mb-fastest inner (A-panel L2-resident).
template <int BM, int BN, int DT, int SPLITK, bool AF32, int CM>
__global__ __launch_bounds__(256) void gemm_t(const void* __restrict__ Ap,
                                              const u16* __restrict__ BT,
                                              const float* __restrict__ bias,
                                              void* __restrict__ Out,
                                              int M, int N, int K) {
    constexpr int WM = BM / 2, WN = BN / 2, MI = WM / 16, NI = WN / 16;
    constexpr bool F16 = (DT == 0 || DT == 3);
    __shared__ __align__(16) u16 As[BM][64];
    __shared__ __align__(16) u16 Bs[BN][64];
    int tid = threadIdx.x, lane = tid & 63, wid = tid >> 6;
    int wr = wid >> 1, wc = wid & 1;

    // bijective XCD swizzle over the whole grid (nwg % 8 == 0 for all our grids)
    int lin = blockIdx.x + gridDim.x * (blockIdx.y + gridDim.y * blockIdx.z);
    int nwg = gridDim.x * gridDim.y * gridDim.z;
    int q = nwg >> 3;
    int logical = (lin & 7) * q + (lin >> 3);
    int Ny = N / BN, Mx = M / BM;
    int mb, nb, z;
    if (CM > 0) {
        z = 0;
        int chunk = logical / (CM * Ny);
        int r2 = logical - chunk * (CM * Ny);
        nb = r2 / CM;
        mb = chunk * CM + (r2 - nb * CM);
    } else {
        int per = Mx * Ny;
        z = logical / per;
        int rem = logical - z * per;
        mb = rem / Ny;
        nb = rem - mb * Ny;
    }
    int m0 = mb * BM, n0 = nb * BN;
    int Ksl = K / SPLITK;
    int kbase = z * Ksl;

    f32x4 acc[MI][NI] = {};
    int NT = Ksl >> 6;
    for (int t = 0; t < NT; ++t) {
        int k0 = kbase + (t << 6);
        if (AF32) {
            const float* Af = (const float*)Ap;
#pragma unroll
            for (int i = 0; i < BM / 16; i++) {
                int s = i * 256 + tid;
                int r = s >> 4, qd = s & 15;
                f32x4 v = *(const f32x4*)(Af + (size_t)(m0 + r) * K + k0 + qd * 4);
                u16 h[4];
#pragma unroll
                for (int j = 0; j < 4; j++) h[j] = __builtin_bit_cast(u16, (_Float16)v[j]);
                int g = qd >> 1;
                int dst = ((g ^ r) & 7) * 16 + (qd & 1) * 8;
                *(uint2*)((char*)&As[r][0] + dst) =
                    make_uint2((unsigned)h[0] | ((unsigned)h[1] << 16),
                               (unsigned)h[2] | ((unsigned)h[3] << 16));
            }
        } else {
            const u16* Au = (const u16*)Ap;
#pragma unroll
            for (int i = 0; i < BM / 32; i++) {
                int s = i * 256 + tid;
                int r = s >> 3, g = s & 7;
                int gs = (g ^ r) & 7;
                gload16(Au + (size_t)(m0 + r) * K + k0 + gs * 8, &As[r][g * 8]);
            }
        }
#pragma unroll
        for (int i = 0; i < BN / 32; i++) {
            int s = i * 256 + tid;
            int r = s >> 3, g = s & 7;
            int gs = (g ^ r) & 7;
            gload16(BT + (size_t)(n0 + r) * K + k0 + gs * 8, &Bs[r][g * 8]);
        }
        __syncthreads();
#pragma unroll
        for (int kk = 0; kk < 2; kk++) {
            int gb = kk * 4 + (lane >> 4);   // K-granule index 0..7
            s16x8 af[MI], bf[NI];
#pragma unroll
            for (int mi = 0; mi < MI; mi++) {
                int r = wr * WM + mi * 16 + (lane & 15);
                af[mi] = *(const s16x8*)&As[r][((gb ^ r) & 7) * 8];
            }
#pragma unroll
            for (int ni = 0; ni < NI; ni++) {
                int r = wc * WN + ni * 16 + (lane & 15);
                bf[ni] = *(const s16x8*)&Bs[r][((gb ^ r) & 7) * 8];
            }
#pragma unroll
            for (int mi = 0; mi < MI; mi++)
#pragma unroll
                for (int ni = 0; ni < NI; ni++) {
                    if (F16)
                        acc[mi][ni] = __builtin_amdgcn_mfma_f32_16x16x32_f16(
                            __builtin_bit_cast(f16x8, af[mi]), __builtin_bit_cast(f16x8, bf[ni]),
                            acc[mi][ni], 0, 0, 0);
                    else
                        acc[mi][ni] = __builtin_amdgcn_mfma_f32_16x16x32_bf16(
                            __builtin_bit_cast(bf16x8, af[mi]), __builtin_bit_cast(bf16x8, bf[ni]),
                            acc[mi][ni], 0, 0, 0);
                }
        }
        __syncthreads();
    }
    float* Outz = (DT == 3) ? (float*)Out + (size_t)z * M * N : (float*)Out;
    float bvv[NI];
#pragma unroll
    for (int ni = 0; ni < NI; ni++)
        bvv[ni] = (DT == 3) ? 0.f : bias[n0 + wc * WN + ni * 16 + (lane & 15)];
    // j-outer, ni-inner: consecutive stores land in adjacent 64B halves of 128B lines
#pragma unroll
    for (int mi = 0; mi < MI; mi++) {
        int rb = m0 + wr * WM + mi * 16 + (lane >> 4) * 4;
#pragma unroll
        for (int j = 0; j < 4; j++) {
            size_t rowo = (size_t)(rb + j) * N;
#pragma unroll
            for (int ni = 0; ni < NI; ni++) {
                int col = n0 + wc * WN + ni * 16 + (lane & 15);
                float x = acc[mi][ni][j];
                if (DT == 3) {
                    __builtin_nontemporal_store(x * (1.0f / 256.0f), &Outz[rowo + col]);
                } else if (DT == 0) {
                    x = x * (1.0f / 256.0f) + bvv[ni];
                    ((float*)Out)[rowo + col] = x > 0.f ? x : 0.f;
                } else if (DT == 1) {
                    x += bvv[ni];
                    ((u16*)Out)[rowo + col] = f2bf_rn(x > 0.f ? x : 0.f);
                } else {
                    x += bvv[ni];
                    __builtin_nontemporal_store(1.f / (1.f + __expf(-x)), &((float*)Out)[rowo + col]);
                }
            }
        }
    }
}

// ---------------- split-K reduce: H = relu(sum_z P[z] + bias), in-place on P[0] ----------------
__global__ __launch_bounds__(256) void reduce_k(float* __restrict__ P, const float* __restrict__ bias,
                                                int total4, int nz, int colmask4) {
    int i = blockIdx.x * 256 + threadIdx.x;
    int stride = gridDim.x * 256;
    for (; i < total4; i += stride) {
        f32x4 a = ((const f32x4*)P)[i];
        for (int zz = 1; zz < nz; zz++) a += ((const f32x4*)P)[i + (size_t)zz * total4];
        f32x4 b = ((const f32x4*)bias)[i & colmask4];
        a += b;
#pragma unroll
        for (int j = 0; j < 4; j++) a[j] = a[j] > 0.f ? a[j] : 0.f;
        ((f32x4*)P)[i] = a;
    }
}

// ---------------- top-64 of 1024 per row: threshold via bit binary search ----------------
__global__ __launch_bounds__(256) void topk_kernel(const float* __restrict__ H,
                                                   u16* __restrict__ HM,
                                                   float* __restrict__ rowT,
                                                   unsigned* __restrict__ rowFlag) {
    int row = blockIdx.x * 4 + (threadIdx.x >> 6);
    int lane = threadIdx.x & 63;
    const float* hr = H + (size_t)row * 1024;
    float v[16];
#pragma unroll
    for (int i = 0; i < 4; i++) *(f32x4*)&v[i * 4] = *(const f32x4*)(hr + lane * 16 + i * 4);
    unsigned u[16];
#pragma unroll
    for (int i = 0; i < 16; i++) u[i] = __float_as_uint(v[i]);
    unsigned lo = 0;
    for (int b = 30; b >= 0; --b) {
        unsigned cand = lo | (1u << b);
        int c = 0;
#pragma unroll
        for (int i = 0; i < 16; i++) c += (u[i] >= cand);
#pragma unroll
        for (int off = 32; off; off >>= 1) c += __shfl_xor(c, off);
        if (c >= 64) lo = cand;
    }
    unsigned m2 = 0;
#pragma unroll
    for (int i = 0; i < 16; i++)
        if (u[i] < lo && u[i] > m2) m2 = u[i];
#pragma unroll
    for (int off = 32; off; off >>= 1) {
        unsigned o = __shfl_xor(m2, off);
        if (o > m2) m2 = o;
    }
    u16 o16[16];
#pragma unroll
    for (int i = 0; i < 16; i++) o16[i] = (u[i] >= lo) ? f2bf_rn(v[i]) : (u16)0;
    unsigned p[8];
#pragma unroll
    for (int i = 0; i < 8; i++) p[i] = (unsigned)o16[2 * i] | ((unsigned)o16[2 * i + 1] << 16);
    u16* dst = HM + (size_t)row * 1024 + lane * 16;
    *(uint4*)dst = make_uint4(p[0], p[1], p[2], p[3]);
    *(uint4*)(dst + 8) = make_uint4(p[4], p[5], p[6], p[7]);
    if (lane == 0) {
        rowT[row] = __uint_as_float(lo);
        float t = __uint_as_float(lo), s = __uint_as_float(m2);
        rowFlag[row] = (lo != 0u) && (t - s < SEL_BAND);
    }
}

// ---------------- fp64 fix-up: 256 thr, wave-per-candidate, 4-chain dots ----------------
__global__ __launch_bounds__(256) void fixup_kernel(const float* __restrict__ H,
                                                    const float* __restrict__ X,
                                                    const float* __restrict__ W,  // [1024][12288] f32 (We1^T)
                                                    const float* __restrict__ be1,
                                                    const float* __restrict__ rowT,
                                                    const unsigned* __restrict__ rowFlag,
                                                    u16* __restrict__ HM) {
    int row = blockIdx.x;
    if (!rowFlag[row]) return;
    int tid = threadIdx.x, lane = tid & 63, wv = tid >> 6;
    float Tf = rowT[row];
    const float* hr = H + (size_t)row * 1024;
    f32x4 v = *(const f32x4*)(hr + tid * 4);
    __shared__ int bidx[64];
    __shared__ float bval[64];
    __shared__ double dval[64];
    __shared__ int cnt, csh;
    if (tid == 0) { cnt = 0; csh = 0; }
    __syncthreads();
    int myS = 0;
#pragma unroll
    for (int i = 0; i < 4; i++) {
        float x = v[i];
        if (fabsf(x - Tf) <= SEL_BAND) {
            int p = atomicAdd(&cnt, 1);
            if (p < 64) { bidx[p] = tid * 4 + i; bval[p] = x; }
        }
        myS += (x > Tf + SEL_BAND);
    }
#pragma unroll
    for (int off = 32; off; off >>= 1) myS += __shfl_xor(myS, off);
    if (lane == 0) atomicAdd(&csh, myS);
    __syncthreads();
    int nb = cnt < 64 ? cnt : 64;
    if (nb < 2) return;
    int kband = 64 - csh;
    const float* xr = X + (size_t)row * 12288;
    for (int e = wv; e < nb; e += 4) {
        const float* wp = W + (size_t)bidx[e] * 12288;
        double s0 = 0, s1 = 0, s2 = 0, s3 = 0;
        for (int k0 = 0; k0 < 12288; k0 += 256) {
            s0 += (double)xr[k0 + lane]       * (double)wp[k0 + lane];
            s1 += (double)xr[k0 + 64 + lane]  * (double)wp[k0 + 64 + lane];
            s2 += (double)xr[k0 + 128 + lane] * (double)wp[k0 + 128 + lane];
            s3 += (double)xr[k0 + 192 + lane] * (double)wp[k0 + 192 + lane];
        }
        double s = (s0 + s1) + (s2 + s3);
#pragma unroll
        for (int off = 32; off; off >>= 1) s += __shfl_xor(s, off);
        if (lane == 0) dval[e] = s + (double)be1[bidx[e]];
    }
    __syncthreads();
    if (tid < nb) {
        double me = dval[tid];
        int j = bidx[tid];
        int rank = 0;
        for (int f = 0; f < nb; f++) {
            double df = dval[f];
            rank += (df > me) || (df == me && bidx[f] < j);
        }
        HM[(size_t)row * 1024 + j] = (rank < kband) ? f2bf_rn(bval[tid]) : (u16)0;
    }
}

extern "C" void kernel_launch(void* const* d_in, const int* in_sizes, int n_in,
                              void* d_out, int out_size, void* d_ws, size_t ws_size,
                              hipStream_t stream) {
    const float* X   = (const float*)d_in[0];
    const float* We1 = (const float*)d_in[1];
    const float* be1 = (const float*)d_in[2];
    const float* Wd1 = (const float*)d_in[3];
    const float* bd1 = (const float*)d_in[4];
    const float* Wd2 = (const float*)d_in[5];
    const float* bd2 = (const float*)d_in[6];

    // workspace tiers: base 136.3 MB (proven) + (SPLITK-1) x 16.8 MB partials
    int splitk = (ws_size >= 187100000ull) ? 4 : (ws_size >= 153600000ull) ? 2 : 1;

    char* ws = (char*)d_ws;
    size_t off = 0;
    auto alloc = [&](size_t bytes) { void* p = ws + off; off += (bytes + 255) & ~(size_t)255; return p; };
    u16* W1hT    = (u16*)alloc(12288ull * 1024 * 2);   // fp16 bits x256, [1024][12288]
    float* We1Tf = (float*)alloc(12288ull * 1024 * 4); // f32 [1024][12288] for fixup
    u16* Wd1T    = (u16*)alloc(1024ull * 1024 * 2);
    u16* Wd2T    = (u16*)alloc(1024ull * 12288 * 2);
    float* Hbuf  = (float*)alloc((size_t)splitk * 4096 * 1024 * 4);  // partial[0] == Hbuf
    u16* HM      = (u16*)alloc(4096ull * 1024 * 2);
    u16* Dbf     = (u16*)alloc(4096ull * 1024 * 2);
    float* rowT  = (float*)alloc(4096 * 4);
    unsigned* rowFlag = (unsigned*)alloc(4096 * 4);

    dim3 tb(32, 8);
    tr_hf<<<dim3(32, 384), tb, 0, stream>>>(We1, 12288, 1024, W1hT, We1Tf);
    tr_bf16<<<dim3(32, 32), tb, 0, stream>>>(Wd1, 1024, 1024, Wd1T);
    tr_bf16<<<dim3(384, 32), tb, 0, stream>>>(Wd2, 1024, 12288, Wd2T);

    if (splitk == 4) {
        gemm_t<128, 128, 3, 4, true, 0><<<dim3(32, 8, 4), 256, 0, stream>>>(X, W1hT, be1, Hbuf, 4096, 1024, 12288);
        reduce_k<<<2048, 256, 0, stream>>>(Hbuf, be1, 4096 * 1024 / 4, 4, 255);
    } else if (splitk == 2) {
        gemm_t<128, 128, 3, 2, true, 0><<<dim3(32, 8, 2), 256, 0, stream>>>(X, W1hT, be1, Hbuf, 4096, 1024, 12288);
        reduce_k<<<2048, 256, 0, stream>>>(Hbuf, be1, 4096 * 1024 / 4, 2, 255);
    } else {
        gemm_t<128, 128, 0, 1, true, 0><<<dim3(32, 8), 256, 0, stream>>>(X, W1hT, be1, Hbuf, 4096, 1024, 12288);
    }
    topk_kernel<<<1024, 256, 0, stream>>>(Hbuf, HM, rowT, rowFlag);
    fixup_kernel<<<4096, 256, 0, stream>>>(Hbuf, X, We1Tf, be1, rowT, rowFlag, HM);
    gemm_t<64, 128, 1, 1, false, 8><<<dim3(64, 8), 256, 0, stream>>>(HM, Wd1T, bd1, Dbf, 4096, 1024, 1024);
    gemm_t<128, 128, 2, 1, false, 4><<<dim3(32, 96), 256, 0, stream>>>(Dbf, Wd2T, bd2, d_out, 4096, 12288, 1024);
}

// Round 9
// 590.086 us; speedup vs baseline: 1.2649x; 1.0170x over previous
//
#include <hip/hip_runtime.h>

typedef float f32x4 __attribute__((ext_vector_type(4)));
typedef __bf16 bf16x8 __attribute__((ext_vector_type(8)));
typedef _Float16 f16x8 __attribute__((ext_vector_type(8)));
typedef short s16x8 __attribute__((ext_vector_type(8)));
typedef unsigned short u16;

#define DEV static __device__ __forceinline__

#define SEL_BAND 2.0e-3f   // fp16-GEMM1 error band for exact re-ranking

DEV u16 f2bf_rn(float f) {
    unsigned u = __float_as_uint(f);
    return (u16)((u + 0x7fffu + ((u >> 16) & 1u)) >> 16);
}

typedef __attribute__((address_space(3))) unsigned int lds_u32;
typedef __attribute__((address_space(1))) const unsigned int glb_u32;

DEV void gload16(const void* g, void* l) {
    __builtin_amdgcn_global_load_lds((glb_u32*)g, (lds_u32*)l, 16, 0, 0);
}

// ---------------- transpose [R][C] f32 -> [C][R] fp16*256 + f32 ----------------
__global__ __launch_bounds__(256) void tr_hf(const float* __restrict__ src, int R, int C,
                                             u16* __restrict__ hT, float* __restrict__ fT) {
    __shared__ float t[32][33];
    int tx = threadIdx.x, ty = threadIdx.y;
    int c0 = blockIdx.x * 32, r0 = blockIdx.y * 32;
#pragma unroll
    for (int i = 0; i < 4; i++) t[ty + i * 8][tx] = src[(size_t)(r0 + ty + i * 8) * C + c0 + tx];
    __syncthreads();
#pragma unroll
    for (int i = 0; i < 4; i++) {
        int c = c0 + ty + i * 8;
        float v = t[tx][ty + i * 8];
        size_t o = (size_t)c * R + r0 + tx;
        hT[o] = __builtin_bit_cast(u16, (_Float16)(v * 256.0f));
        fT[o] = v;
    }
}

// ---------------- transpose [R][C] f32 -> [C][R] bf16 ----------------
__global__ __launch_bounds__(256) void tr_bf16(const float* __restrict__ src, int R, int C,
                                               u16* __restrict__ dst) {
    __shared__ float t[32][33];
    int tx = threadIdx.x, ty = threadIdx.y;
    int c0 = blockIdx.x * 32, r0 = blockIdx.y * 32;
#pragma unroll
    for (int i = 0; i < 4; i++) t[ty + i * 8][tx] = src[(size_t)(r0 + ty + i * 8) * C + c0 + tx];
    __syncthreads();
#pragma unroll
    for (int i = 0; i < 4; i++)
        dst[(size_t)(c0 + ty + i * 8) * R + r0 + tx] = f2bf_rn(t[tx][ty + i * 8]);
}

// ---------------- GEMM1: 128x128, split-K, A = f32 via global_load_lds, cvt->f16 on read ----------------
// Out: SPLITK>1 -> raw acc/256 partials [z][M][N] (nt-store); SPLITK==1 -> relu(acc/256+bias)
template <int SPLITK>
__global__ __launch_bounds__(256) void gemm1_k(const float* __restrict__ A,
                                               const u16* __restrict__ BT,
                                               const float* __restrict__ bias,
                                               float* __restrict__ Out,
                                               int M, int N, int K) {
    __shared__ __align__(16) float Af[128][64];  // 32 KB, granule16 = 4 f32
    __shared__ __align__(16) u16 Bs[128][64];    // 16 KB, granule16 = 8 halfs
    int tid = threadIdx.x, lane = tid & 63, wid = tid >> 6;
    int wr = wid >> 1, wc = wid & 1;

    int lin = blockIdx.x + gridDim.x * (blockIdx.y + gridDim.y * blockIdx.z);
    int nwg = gridDim.x * gridDim.y * gridDim.z;
    int q = nwg >> 3;
    int logical = (lin & 7) * q + (lin >> 3);
    int Ny = N >> 7;
    int per = (M >> 7) * Ny;
    int z = logical / per;
    int rem = logical - z * per;
    int mb = rem / Ny, nb = rem - mb * Ny;
    int m0 = mb << 7, n0 = nb << 7;
    int Ksl = K / SPLITK;
    int kbase = z * Ksl;

    f32x4 acc[4][4] = {};
    int NT = Ksl >> 6;
    for (int t = 0; t < NT; ++t) {
        int k0 = kbase + (t << 6);
        // A: 128 rows x 16 f32-granules, source-swizzled
#pragma unroll
        for (int i = 0; i < 8; i++) {
            int s = i * 256 + tid;
            int r = s >> 4, g = s & 15;
            int gs = (g & 8) | ((g ^ r) & 7);
            gload16(A + (size_t)(m0 + r) * K + k0 + gs * 4, &Af[r][g * 4]);
        }
#pragma unroll
        for (int i = 0; i < 4; i++) {
            int s = i * 256 + tid;
            int r = s >> 3, g = s & 7;
            int gs = (g ^ r) & 7;
            gload16(BT + (size_t)(n0 + r) * K + k0 + gs * 8, &Bs[r][g * 8]);
        }
        __syncthreads();
#pragma unroll
        for (int kk = 0; kk < 2; kk++) {
            int gb = kk * 4 + (lane >> 4);     // 8-half granule 0..7
            f16x8 af[4]; s16x8 bf[4];
#pragma unroll
            for (int mi = 0; mi < 4; mi++) {
                int r = wr * 64 + mi * 16 + (lane & 15);
                int ra = r & 7;
                int g0 = gb * 2;
                f32x4 lo4 = *(const f32x4*)&Af[r][(((g0 ^ ra) & 7) | (g0 & 8)) * 4];
                f32x4 hi4 = *(const f32x4*)&Af[r][((((g0 + 1) ^ ra) & 7) | ((g0 + 1) & 8)) * 4];
                f16x8 tv;
#pragma unroll
                for (int j = 0; j < 4; j++) { tv[j] = (_Float16)lo4[j]; tv[j + 4] = (_Float16)hi4[j]; }
                af[mi] = tv;
            }
#pragma unroll
            for (int ni = 0; ni < 4; ni++) {
                int r = wc * 64 + ni * 16 + (lane & 15);
                bf[ni] = *(const s16x8*)&Bs[r][((gb ^ r) & 7) * 8];
            }
#pragma unroll
            for (int mi = 0; mi < 4; mi++)
#pragma unroll
                for (int ni = 0; ni < 4; ni++)
                    acc[mi][ni] = __builtin_amdgcn_mfma_f32_16x16x32_f16(
                        af[mi], __builtin_bit_cast(f16x8, bf[ni]), acc[mi][ni], 0, 0, 0);
        }
        __syncthreads();
    }
    float* Outz = Out + (size_t)z * M * N;
    float bvv[4];
#pragma unroll
    for (int ni = 0; ni < 4; ni++)
        bvv[ni] = (SPLITK > 1) ? 0.f : bias[n0 + wc * 64 + ni * 16 + (lane & 15)];
#pragma unroll
    for (int mi = 0; mi < 4; mi++) {
        int rb = m0 + wr * 64 + mi * 16 + (lane >> 4) * 4;
#pragma unroll
        for (int j = 0; j < 4; j++) {
            size_t rowo = (size_t)(rb + j) * N;
#pragma unroll
            for (int ni = 0; ni < 4; ni++) {
                int col = n0 + wc * 64 + ni * 16 + (lane & 15);
                float x = acc[mi][ni][j] * (1.0f / 256.0f);
                if (SPLITK > 1) {
                    __builtin_nontemporal_store(x, &Outz[rowo + col]);
                } else {
                    x += bvv[ni];
                    Out[rowo + col] = x > 0.f ? x : 0.f;
                }
            }
        }
    }
}

// ---------------- GEMM2: 64x128 bf16, relu -> bf16, CM=8 chunked ----------------
__global__ __launch_bounds__(256) void gemm2_k(const u16* __restrict__ A,
                                               const u16* __restrict__ BT,
                                               const float* __restrict__ bias,
                                               u16* __restrict__ Out,
                                               int M, int N, int K) {
    __shared__ __align__(16) u16 As[64][64];
    __shared__ __align__(16) u16 Bs[128][64];
    int tid = threadIdx.x, lane = tid & 63, wid = tid >> 6;
    int wr = wid >> 1, wc = wid & 1;
    int lin = blockIdx.x + gridDim.x * blockIdx.y;
    int nwg = gridDim.x * gridDim.y;
    int q = nwg >> 3;
    int logical = (lin & 7) * q + (lin >> 3);
    int Ny = N >> 7;
    int chunk = logical / (8 * Ny);
    int r2 = logical - chunk * (8 * Ny);
    int nb = r2 >> 3, mb = chunk * 8 + (r2 & 7);
    int m0 = mb << 6, n0 = nb << 7;
    f32x4 acc[2][4] = {};
    int NT = K >> 6;
    for (int t = 0; t < NT; ++t) {
        int k0 = t << 6;
#pragma unroll
        for (int i = 0; i < 2; i++) {
            int s = i * 256 + tid;
            int r = s >> 3, g = s & 7;
            int gs = (g ^ r) & 7;
            gload16(A + (size_t)(m0 + r) * K + k0 + gs * 8, &As[r][g * 8]);
        }
#pragma unroll
        for (int i = 0; i < 4; i++) {
            int s = i * 256 + tid;
            int r = s >> 3, g = s & 7;
            int gs = (g ^ r) & 7;
            gload16(BT + (size_t)(n0 + r) * K + k0 + gs * 8, &Bs[r][g * 8]);
        }
        __syncthreads();
#pragma unroll
        for (int kk = 0; kk < 2; kk++) {
            int gb = kk * 4 + (lane >> 4);
            s16x8 af[2], bf[4];
#pragma unroll
            for (int mi = 0; mi < 2; mi++) {
                int r = wr * 32 + mi * 16 + (lane & 15);
                af[mi] = *(const s16x8*)&As[r][((gb ^ r) & 7) * 8];
            }
#pragma unroll
            for (int ni = 0; ni < 4; ni++) {
                int r = wc * 64 + ni * 16 + (lane & 15);
                bf[ni] = *(const s16x8*)&Bs[r][((gb ^ r) & 7) * 8];
            }
#pragma unroll
            for (int mi = 0; mi < 2; mi++)
#pragma unroll
                for (int ni = 0; ni < 4; ni++)
                    acc[mi][ni] = __builtin_amdgcn_mfma_f32_16x16x32_bf16(
                        __builtin_bit_cast(bf16x8, af[mi]), __builtin_bit_cast(bf16x8, bf[ni]),
                        acc[mi][ni], 0, 0, 0);
        }
        __syncthreads();
    }
#pragma unroll
    for (int mi = 0; mi < 2; mi++) {
        int rb = m0 + wr * 32 + mi * 16 + (lane >> 4) * 4;
#pragma unroll
        for (int j = 0; j < 4; j++) {
            size_t rowo = (size_t)(rb + j) * N;
#pragma unroll
            for (int ni = 0; ni < 4; ni++) {
                int col = n0 + wc * 64 + ni * 16 + (lane & 15);
                float x = acc[mi][ni][j] + bias[col];
                Out[rowo + col] = f2bf_rn(x > 0.f ? x : 0.f);
            }
        }
    }
}

// ---------------- GEMM3: 256x256 bf16, 8 waves, sigmoid -> f32 nt-store, CM=2 chunked ----------------
__global__ __launch_bounds__(512) void gemm3_k(const u16* __restrict__ A,
                                               const u16* __restrict__ BT,
                                               const float* __restrict__ bias,
                                               float* __restrict__ Out,
                                               int M, int N, int K) {
    __shared__ __align__(16) u16 As[256][64];   // 32 KB
    __shared__ __align__(16) u16 Bs[256][64];   // 32 KB
    int tid = threadIdx.x, lane = tid & 63, wid = tid >> 6;
    int wr = wid >> 2, wc = wid & 3;            // 2 x 4 waves
    int lin = blockIdx.x + gridDim.x * blockIdx.y;
    int nwg = gridDim.x * gridDim.y;
    int q = nwg >> 3;
    int logical = (lin & 7) * q + (lin >> 3);
    int Ny = N >> 8;                            // 48
    int chunk = logical / (2 * Ny);
    int r2 = logical - chunk * (2 * Ny);
    int nb = r2 >> 1, mb = chunk * 2 + (r2 & 1);
    int m0 = mb << 8, n0 = nb << 8;

    f32x4 acc[8][4] = {};
    int NT = K >> 6;
    for (int t = 0; t < NT; ++t) {
        int k0 = t << 6;
#pragma unroll
        for (int i = 0; i < 4; i++) {
            int s = i * 512 + tid;
            int r = s >> 3, g = s & 7;
            int gs = (g ^ r) & 7;
            gload16(A + (size_t)(m0 + r) * K + k0 + gs * 8, &As[r][g * 8]);
        }
#pragma unroll
        for (int i = 0; i < 4; i++) {
            int s = i * 512 + tid;
            int r = s >> 3, g = s & 7;
            int gs = (g ^ r) & 7;
            gload16(BT + (size_t)(n0 + r) * K + k0 + gs * 8, &Bs[r][g * 8]);
        }
        __syncthreads();
#pragma unroll
        for (int kk = 0; kk < 2; kk++) {
            int gb = kk * 4 + (lane >> 4);
            s16x8 af[8], bf[4];
#pragma unroll
            for (int mi = 0; mi < 8; mi++) {
                int r = wr * 128 + mi * 16 + (lane & 15);
                af[mi] = *(const s16x8*)&As[r][((gb ^ r) & 7) * 8];
            }
#pragma unroll
            for (int ni = 0; ni < 4; ni++) {
                int r = wc * 64 + ni * 16 + (lane & 15);
                bf[ni] = *(const s16x8*)&Bs[r][((gb ^ r) & 7) * 8];
            }
#pragma unroll
            for (int mi = 0; mi < 8; mi++)
#pragma unroll
                for (int ni = 0; ni < 4; ni++)
                    acc[mi][ni] = __builtin_amdgcn_mfma_f32_16x16x32_bf16(
                        __builtin_bit_cast(bf16x8, af[mi]), __builtin_bit_cast(bf16x8, bf[ni]),
                        acc[mi][ni], 0, 0, 0);
        }
        __syncthreads();
    }
    float bvv[4];
#pragma unroll
    for (int ni = 0; ni < 4; ni++) bvv[ni] = bias[n0 + wc * 64 + ni * 16 + (lane & 15)];
#pragma unroll
    for (int mi = 0; mi < 8; mi++) {
        int rb = m0 + wr * 128 + mi * 16 + (lane >> 4) * 4;
#pragma unroll
        for (int j = 0; j < 4; j++) {
            size_t rowo = (size_t)(rb + j) * N;
#pragma unroll
            for (int ni = 0; ni < 4; ni++) {
                int col = n0 + wc * 64 + ni * 16 + (lane & 15);
                float x = acc[mi][ni][j] + bvv[ni];
                __builtin_nontemporal_store(1.f / (1.f + __expf(-x)), &Out[rowo + col]);
            }
        }
    }
}

// ---------------- split-K reduce: H = relu(sum_z P[z] + bias), in-place on P[0] ----------------
__global__ __launch_bounds__(256) void reduce_k(float* __restrict__ P, const float* __restrict__ bias,
                                                int total4, int nz, int colmask4) {
    int i = blockIdx.x * 256 + threadIdx.x;
    int stride = gridDim.x * 256;
    for (; i < total4; i += stride) {
        f32x4 a = ((const f32x4*)P)[i];
        for (int zz = 1; zz < nz; zz++) a += ((const f32x4*)P)[i + (size_t)zz * total4];
        f32x4 b = ((const f32x4*)bias)[i & colmask4];
        a += b;
#pragma unroll
        for (int j = 0; j < 4; j++) a[j] = a[j] > 0.f ? a[j] : 0.f;
        ((f32x4*)P)[i] = a;
    }
}

// ---------------- top-64 of 1024 per row: threshold via bit binary search ----------------
__global__ __launch_bounds__(256) void topk_kernel(const float* __restrict__ H,
                                                   u16* __restrict__ HM,
                                                   float* __restrict__ rowT,
                                                   unsigned* __restrict__ rowFlag) {
    int row = blockIdx.x * 4 + (threadIdx.x >> 6);
    int lane = threadIdx.x & 63;
    const float* hr = H + (size_t)row * 1024;
    float v[16];
#pragma unroll
    for (int i = 0; i < 4; i++) *(f32x4*)&v[i * 4] = *(const f32x4*)(hr + lane * 16 + i * 4);
    unsigned u[16];
#pragma unroll
    for (int i = 0; i < 16; i++) u[i] = __float_as_uint(v[i]);
    unsigned lo = 0;
    for (int b = 30; b >= 0; --b) {
        unsigned cand = lo | (1u << b);
        int c = 0;
#pragma unroll
        for (int i = 0; i < 16; i++) c += (u[i] >= cand);
#pragma unroll
        for (int off = 32; off; off >>= 1) c += __shfl_xor(c, off);
        if (c >= 64) lo = cand;
    }
    unsigned m2 = 0;
#pragma unroll
    for (int i = 0; i < 16; i++)
        if (u[i] < lo && u[i] > m2) m2 = u[i];
#pragma unroll
    for (int off = 32; off; off >>= 1) {
        unsigned o = __shfl_xor(m2, off);
        if (o > m2) m2 = o;
    }
    u16 o16[16];
#pragma unroll
    for (int i = 0; i < 16; i++) o16[i] = (u[i] >= lo) ? f2bf_rn(v[i]) : (u16)0;
    unsigned p[8];
#pragma unroll
    for (int i = 0; i < 8; i++) p[i] = (unsigned)o16[2 * i] | ((unsigned)o16[2 * i + 1] << 16);
    u16* dst = HM + (size_t)row * 1024 + lane * 16;
    *(uint4*)dst = make_uint4(p[0], p[1], p[2], p[3]);
    *(uint4*)(dst + 8) = make_uint4(p[4], p[5], p[6], p[7]);
    if (lane == 0) {
        rowT[row] = __uint_as_float(lo);
        float t = __uint_as_float(lo), s = __uint_as_float(m2);
        rowFlag[row] = (lo != 0u) && (t - s < SEL_BAND);
    }
}

// ---------------- fp64 fix-up: 256 thr, wave-per-candidate, 4-chain dots ----------------
__global__ __launch_bounds__(256) void fixup_kernel(const float* __restrict__ H,
                                                    const float* __restrict__ X,
                                                    const float* __restrict__ W,  // [1024][12288] f32 (We1^T)
                                                    const float* __restrict__ be1,
                                                    const float* __restrict__ rowT,
                                                    const unsigned* __restrict__ rowFlag,
                                                    u16* __restrict__ HM) {
    int row = blockIdx.x;
    if (!rowFlag[row]) return;
    int tid = threadIdx.x, lane = tid & 63, wv = tid >> 6;
    float Tf = rowT[row];
    const float* hr = H + (size_t)row * 1024;
    f32x4 v = *(const f32x4*)(hr + tid * 4);
    __shared__ int bidx[64];
    __shared__ float bval[64];
    __shared__ double dval[64];
    __shared__ int cnt, csh;
    if (tid == 0) { cnt = 0; csh = 0; }
    __syncthreads();
    int myS = 0;
#pragma unroll
    for (int i = 0; i < 4; i++) {
        float x = v[i];
        if (fabsf(x - Tf) <= SEL_BAND) {
            int p = atomicAdd(&cnt, 1);
            if (p < 64) { bidx[p] = tid * 4 + i; bval[p] = x; }
        }
        myS += (x > Tf + SEL_BAND);
    }
#pragma unroll
    for (int off = 32; off; off >>= 1) myS += __shfl_xor(myS, off);
    if (lane == 0) atomicAdd(&csh, myS);
    __syncthreads();
    int nb = cnt < 64 ? cnt : 64;
    if (nb < 2) return;
    int kband = 64 - csh;
    const float* xr = X + (size_t)row * 12288;
    for (int e = wv; e < nb; e += 4) {
        const float* wp = W + (size_t)bidx[e] * 12288;
        double s0 = 0, s1 = 0, s2 = 0, s3 = 0;
        for (int k0 = 0; k0 < 12288; k0 += 256) {
            s0 += (double)xr[k0 + lane]       * (double)wp[k0 + lane];
            s1 += (double)xr[k0 + 64 + lane]  * (double)wp[k0 + 64 + lane];
            s2 += (double)xr[k0 + 128 + lane] * (double)wp[k0 + 128 + lane];
            s3 += (double)xr[k0 + 192 + lane] * (double)wp[k0 + 192 + lane];
        }
        double s = (s0 + s1) + (s2 + s3);
#pragma unroll
        for (int off = 32; off; off >>= 1) s += __shfl_xor(s, off);
        if (lane == 0) dval[e] = s + (double)be1[bidx[e]];
    }
    __syncthreads();
    if (tid < nb) {
        double me = dval[tid];
        int j = bidx[tid];
        int rank = 0;
        for (int f = 0; f < nb; f++) {
            double df = dval[f];
            rank += (df > me) || (df == me && bidx[f] < j);
        }
        HM[(size_t)row * 1024 + j] = (rank < kband) ? f2bf_rn(bval[tid]) : (u16)0;
    }
}

extern "C" void kernel_launch(void* const* d_in, const int* in_sizes, int n_in,
                              void* d_out, int out_size, void* d_ws, size_t ws_size,
                              hipStream_t stream) {
    const float* X   = (const float*)d_in[0];
    const float* We1 = (const float*)d_in[1];
    const float* be1 = (const float*)d_in[2];
    const float* Wd1 = (const float*)d_in[3];
    const float* bd1 = (const float*)d_in[4];
    const float* Wd2 = (const float*)d_in[5];
    const float* bd2 = (const float*)d_in[6];

    // workspace tiers: base 136.3 MB (proven) + (SPLITK-1) x 16.8 MB partials
    int splitk = (ws_size >= 187100000ull) ? 4 : (ws_size >= 153600000ull) ? 2 : 1;

    char* ws = (char*)d_ws;
    size_t off = 0;
    auto alloc = [&](size_t bytes) { void* p = ws + off; off += (bytes + 255) & ~(size_t)255; return p; };
    u16* W1hT    = (u16*)alloc(12288ull * 1024 * 2);   // fp16 bits x256, [1024][12288]
    float* We1Tf = (float*)alloc(12288ull * 1024 * 4); // f32 [1024][12288] for fixup
    u16* Wd1T    = (u16*)alloc(1024ull * 1024 * 2);
    u16* Wd2T    = (u16*)alloc(1024ull * 12288 * 2);
    float* Hbuf  = (float*)alloc((size_t)splitk * 4096 * 1024 * 4);  // partial[0] == Hbuf
    u16* HM      = (u16*)alloc(4096ull * 1024 * 2);
    u16* Dbf     = (u16*)alloc(4096ull * 1024 * 2);
    float* rowT  = (float*)alloc(4096 * 4);
    unsigned* rowFlag = (unsigned*)alloc(4096 * 4);

    dim3 tb(32, 8);
    tr_hf<<<dim3(32, 384), tb, 0, stream>>>(We1, 12288, 1024, W1hT, We1Tf);
    tr_bf16<<<dim3(32, 32), tb, 0, stream>>>(Wd1, 1024, 1024, Wd1T);
    tr_bf16<<<dim3(384, 32), tb, 0, stream>>>(Wd2, 1024, 12288, Wd2T);

    if (splitk == 4) {
        gemm1_k<4><<<dim3(32, 8, 4), 256, 0, stream>>>(X, W1hT, be1, Hbuf, 4096, 1024, 12288);
        reduce_k<<<2048, 256, 0, stream>>>(Hbuf, be1, 4096 * 1024 / 4, 4, 255);
    } else if (splitk == 2) {
        gemm1_k<2><<<dim3(32, 8, 2), 256, 0, stream>>>(X, W1hT, be1, Hbuf, 4096, 1024, 12288);
        reduce_k<<<2048, 256, 0, stream>>>(Hbuf, be1, 4096 * 1024 / 4, 2, 255);
    } else {
        gemm1_k<1><<<dim3(32, 8), 256, 0, stream>>>(X, W1hT, be1, Hbuf, 4096, 1024, 12288);
    }
    topk_kernel<<<1024, 256, 0, stream>>>(Hbuf, HM, rowT, rowFlag);
    fixup_kernel<<<4096, 256, 0, stream>>>(Hbuf, X, We1Tf, be1, rowT, rowFlag, HM);
    gemm2_k<<<dim3(64, 8), 256, 0, stream>>>(HM, Wd1T, bd1, Dbf, 4096, 1024, 1024);
    gemm3_k<<<dim3(16, 48), 512, 0, stream>>>(Dbf, Wd2T, bd2, (float*)d_out, 4096, 12288, 1024);
}

// Round 10
// 531.333 us; speedup vs baseline: 1.4048x; 1.1106x over previous
//
#include <hip/hip_runtime.h>

typedef float f32x4 __attribute__((ext_vector_type(4)));
typedef __bf16 bf16x8 __attribute__((ext_vector_type(8)));
typedef _Float16 f16x8 __attribute__((ext_vector_type(8)));
typedef short s16x8 __attribute__((ext_vector_type(8)));
typedef unsigned short u16;

#define DEV static __device__ __forceinline__

#define SEL_BAND 2.0e-3f   // fp16-GEMM1 error band for exact re-ranking

DEV u16 f2bf_rn(float f) {
    unsigned u = __float_as_uint(f);
    return (u16)((u + 0x7fffu + ((u >> 16) & 1u)) >> 16);
}

typedef __attribute__((address_space(3))) unsigned int lds_u32;
typedef __attribute__((address_space(1))) const unsigned int glb_u32;

DEV void gload16(const void* g, void* l) {
    __builtin_amdgcn_global_load_lds((glb_u32*)g, (lds_u32*)l, 16, 0, 0);
}
DEV void bar_raw() { asm volatile("s_barrier" ::: "memory"); }
DEV void wait_vm8() { asm volatile("s_waitcnt vmcnt(8)" ::: "memory"); }
DEV void wait_vm0() { asm volatile("s_waitcnt vmcnt(0)" ::: "memory"); }

// ---------------- transpose [R][C] f32 -> [C][R] fp16*256 + f32 ----------------
__global__ __launch_bounds__(256) void tr_hf(const float* __restrict__ src, int R, int C,
                                             u16* __restrict__ hT, float* __restrict__ fT) {
    __shared__ float t[32][33];
    int tx = threadIdx.x, ty = threadIdx.y;
    int c0 = blockIdx.x * 32, r0 = blockIdx.y * 32;
#pragma unroll
    for (int i = 0; i < 4; i++) t[ty + i * 8][tx] = src[(size_t)(r0 + ty + i * 8) * C + c0 + tx];
    __syncthreads();
#pragma unroll
    for (int i = 0; i < 4; i++) {
        int c = c0 + ty + i * 8;
        float v = t[tx][ty + i * 8];
        size_t o = (size_t)c * R + r0 + tx;
        hT[o] = __builtin_bit_cast(u16, (_Float16)(v * 256.0f));
        fT[o] = v;
    }
}

// ---------------- transpose [R][C] f32 -> [C][R] bf16 ----------------
__global__ __launch_bounds__(256) void tr_bf16(const float* __restrict__ src, int R, int C,
                                               u16* __restrict__ dst) {
    __shared__ float t[32][33];
    int tx = threadIdx.x, ty = threadIdx.y;
    int c0 = blockIdx.x * 32, r0 = blockIdx.y * 32;
#pragma unroll
    for (int i = 0; i < 4; i++) t[ty + i * 8][tx] = src[(size_t)(r0 + ty + i * 8) * C + c0 + tx];
    __syncthreads();
#pragma unroll
    for (int i = 0; i < 4; i++)
        dst[(size_t)(c0 + ty + i * 8) * R + r0 + tx] = f2bf_rn(t[tx][ty + i * 8]);
}

// ---------------- GEMM1: 128x256, 8 waves, split-K, dbuf + counted vmcnt pipeline ----------------
// A = f32 via global_load_lds (swizzled granules), cvt->f16 on fragment read.
// SPLITK>1 -> raw acc/256 partials [z][M][N] nt-store; ==1 -> relu(acc/256+bias).
template <int SPLITK>
__global__ __launch_bounds__(512) void gemm1_k(const float* __restrict__ A,
                                               const u16* __restrict__ BT,
                                               const float* __restrict__ bias,
                                               float* __restrict__ Out,
                                               int M, int N, int K) {
    constexpr int ABYT = 128 * 64 * 4;   // 32 KB f32
    constexpr int BBYT = 256 * 64 * 2;   // 32 KB bf16/f16 bits
    __shared__ __align__(16) char lds[2][ABYT + BBYT];
    int tid = threadIdx.x, lane = tid & 63, wid = tid >> 6;
    int wr = wid >> 2, wc = wid & 3;    // 2 x 4 waves, WM=64, WN=64

    int lin = blockIdx.x + gridDim.x * (blockIdx.y + gridDim.y * blockIdx.z);
    int nwg = gridDim.x * gridDim.y * gridDim.z;
    int q = nwg >> 3;
    int logical = (lin & 7) * q + (lin >> 3);
    int Ny = N >> 8;                     // 256-wide N tiles
    int per = (M >> 7) * Ny;
    int z = logical / per;
    int rem = logical - z * per;
    int mb = rem / Ny, nb = rem - mb * Ny;
    int m0 = mb << 7, n0 = nb << 8;
    int Ksl = K / SPLITK;
    int kbase = z * Ksl;
    int NT = Ksl >> 6;

    auto stage = [&](int t, int c) {
        int k0 = kbase + (t << 6);
        char* bA = lds[c];
        char* bB = lds[c] + ABYT;
#pragma unroll
        for (int i = 0; i < 4; i++) {    // A: 128 rows x 16 f32-granules
            int s = i * 512 + tid;
            int r = s >> 4, g = s & 15;
            int gs = (g & 8) | ((g ^ r) & 7);
            gload16(A + (size_t)(m0 + r) * K + k0 + gs * 4, bA + r * 256 + g * 16);
        }
#pragma unroll
        for (int i = 0; i < 4; i++) {    // B: 256 rows x 8 half-granules
            int s = i * 512 + tid;
            int r = s >> 3, g = s & 7;
            int gs = (g ^ r) & 7;
            gload16(BT + (size_t)(n0 + r) * K + k0 + gs * 8, bB + r * 128 + g * 16);
        }
    };

    f32x4 acc[4][4] = {};
    stage(0, 0);
    if (NT > 1) stage(1, 1);
    for (int t = 0; t < NT; ++t) {
        if (t + 1 < NT) wait_vm8(); else wait_vm0();
        bar_raw();
        const float* Af = (const float*)lds[t & 1];
        const u16* Bs = (const u16*)(lds[t & 1] + ABYT);
#pragma unroll
        for (int kk = 0; kk < 2; kk++) {
            int gb = kk * 4 + (lane >> 4);
            f16x8 af[4]; s16x8 bf[4];
#pragma unroll
            for (int mi = 0; mi < 4; mi++) {
                int r = wr * 64 + mi * 16 + (lane & 15);
                int ra = r & 7;
                int g0 = gb * 2;
                f32x4 lo4 = *(const f32x4*)&Af[r * 64 + (((g0 ^ ra) & 7) | (g0 & 8)) * 4];
                f32x4 hi4 = *(const f32x4*)&Af[r * 64 + ((((g0 + 1) ^ ra) & 7) | ((g0 + 1) & 8)) * 4];
                f16x8 tv;
#pragma unroll
                for (int j = 0; j < 4; j++) { tv[j] = (_Float16)lo4[j]; tv[j + 4] = (_Float16)hi4[j]; }
                af[mi] = tv;
            }
#pragma unroll
            for (int ni = 0; ni < 4; ni++) {
                int r = wc * 64 + ni * 16 + (lane & 15);
                bf[ni] = *(const s16x8*)&Bs[r * 64 + ((gb ^ r) & 7) * 8];
            }
#pragma unroll
            for (int mi = 0; mi < 4; mi++)
#pragma unroll
                for (int ni = 0; ni < 4; ni++)
                    acc[mi][ni] = __builtin_amdgcn_mfma_f32_16x16x32_f16(
                        af[mi], __builtin_bit_cast(f16x8, bf[ni]), acc[mi][ni], 0, 0, 0);
        }
        bar_raw();
        if (t + 2 < NT) stage(t + 2, t & 1);
    }
    float* Outz = Out + (size_t)z * M * N;
    float bvv[4];
#pragma unroll
    for (int ni = 0; ni < 4; ni++)
        bvv[ni] = (SPLITK > 1) ? 0.f : bias[n0 + wc * 64 + ni * 16 + (lane & 15)];
#pragma unroll
    for (int mi = 0; mi < 4; mi++) {
        int rb = m0 + wr * 64 + mi * 16 + (lane >> 4) * 4;
#pragma unroll
        for (int j = 0; j < 4; j++) {
            size_t rowo = (size_t)(rb + j) * N;
#pragma unroll
            for (int ni = 0; ni < 4; ni++) {
                int col = n0 + wc * 64 + ni * 16 + (lane & 15);
                float x = acc[mi][ni][j] * (1.0f / 256.0f);
                if (SPLITK > 1) {
                    __builtin_nontemporal_store(x, &Outz[rowo + col]);
                } else {
                    x += bvv[ni];
                    Out[rowo + col] = x > 0.f ? x : 0.f;
                }
            }
        }
    }
}

// ---------------- GEMM2: 64x128 bf16, relu -> bf16, CM=8 chunked ----------------
__global__ __launch_bounds__(256) void gemm2_k(const u16* __restrict__ A,
                                               const u16* __restrict__ BT,
                                               const float* __restrict__ bias,
                                               u16* __restrict__ Out,
                                               int M, int N, int K) {
    __shared__ __align__(16) u16 As[64][64];
    __shared__ __align__(16) u16 Bs[128][64];
    int tid = threadIdx.x, lane = tid & 63, wid = tid >> 6;
    int wr = wid >> 1, wc = wid & 1;
    int lin = blockIdx.x + gridDim.x * blockIdx.y;
    int nwg = gridDim.x * gridDim.y;
    int q = nwg >> 3;
    int logical = (lin & 7) * q + (lin >> 3);
    int Ny = N >> 7;
    int chunk = logical / (8 * Ny);
    int r2 = logical - chunk * (8 * Ny);
    int nb = r2 >> 3, mb = chunk * 8 + (r2 & 7);
    int m0 = mb << 6, n0 = nb << 7;
    f32x4 acc[2][4] = {};
    int NT = K >> 6;
    for (int t = 0; t < NT; ++t) {
        int k0 = t << 6;
#pragma unroll
        for (int i = 0; i < 2; i++) {
            int s = i * 256 + tid;
            int r = s >> 3, g = s & 7;
            int gs = (g ^ r) & 7;
            gload16(A + (size_t)(m0 + r) * K + k0 + gs * 8, &As[r][g * 8]);
        }
#pragma unroll
        for (int i = 0; i < 4; i++) {
            int s = i * 256 + tid;
            int r = s >> 3, g = s & 7;
            int gs = (g ^ r) & 7;
            gload16(BT + (size_t)(n0 + r) * K + k0 + gs * 8, &Bs[r][g * 8]);
        }
        __syncthreads();
#pragma unroll
        for (int kk = 0; kk < 2; kk++) {
            int gb = kk * 4 + (lane >> 4);
            s16x8 af[2], bf[4];
#pragma unroll
            for (int mi = 0; mi < 2; mi++) {
                int r = wr * 32 + mi * 16 + (lane & 15);
                af[mi] = *(const s16x8*)&As[r][((gb ^ r) & 7) * 8];
            }
#pragma unroll
            for (int ni = 0; ni < 4; ni++) {
                int r = wc * 64 + ni * 16 + (lane & 15);
                bf[ni] = *(const s16x8*)&Bs[r][((gb ^ r) & 7) * 8];
            }
#pragma unroll
            for (int mi = 0; mi < 2; mi++)
#pragma unroll
                for (int ni = 0; ni < 4; ni++)
                    acc[mi][ni] = __builtin_amdgcn_mfma_f32_16x16x32_bf16(
                        __builtin_bit_cast(bf16x8, af[mi]), __builtin_bit_cast(bf16x8, bf[ni]),
                        acc[mi][ni], 0, 0, 0);
        }
        __syncthreads();
    }
#pragma unroll
    for (int mi = 0; mi < 2; mi++) {
        int rb = m0 + wr * 32 + mi * 16 + (lane >> 4) * 4;
#pragma unroll
        for (int j = 0; j < 4; j++) {
            size_t rowo = (size_t)(rb + j) * N;
#pragma unroll
            for (int ni = 0; ni < 4; ni++) {
                int col = n0 + wc * 64 + ni * 16 + (lane & 15);
                float x = acc[mi][ni][j] + bias[col];
                Out[rowo + col] = f2bf_rn(x > 0.f ? x : 0.f);
            }
        }
    }
}

// ---------------- GEMM3: 256x256 bf16, 8 waves, dbuf + counted vmcnt, sigmoid nt-store ----------------
__global__ __launch_bounds__(512) void gemm3_k(const u16* __restrict__ A,
                                               const u16* __restrict__ BT,
                                               const float* __restrict__ bias,
                                               float* __restrict__ Out,
                                               int M, int N, int K) {
    constexpr int ABYT = 256 * 64 * 2;   // 32 KB
    __shared__ __align__(16) char lds[2][2 * ABYT];
    int tid = threadIdx.x, lane = tid & 63, wid = tid >> 6;
    int wr = wid >> 2, wc = wid & 3;     // 2 x 4 waves
    int lin = blockIdx.x + gridDim.x * blockIdx.y;
    int nwg = gridDim.x * gridDim.y;
    int q = nwg >> 3;
    int logical = (lin & 7) * q + (lin >> 3);
    int Ny = N >> 8;
    int chunk = logical / (2 * Ny);
    int r2 = logical - chunk * (2 * Ny);
    int nb = r2 >> 1, mb = chunk * 2 + (r2 & 1);
    int m0 = mb << 8, n0 = nb << 8;
    int NT = K >> 6;

    auto stage = [&](int t, int c) {
        int k0 = t << 6;
        u16* As = (u16*)lds[c];
        u16* Bs = (u16*)(lds[c] + ABYT);
#pragma unroll
        for (int i = 0; i < 4; i++) {
            int s = i * 512 + tid;
            int r = s >> 3, g = s & 7;
            int gs = (g ^ r) & 7;
            gload16(A + (size_t)(m0 + r) * K + k0 + gs * 8, As + r * 64 + g * 8);
        }
#pragma unroll
        for (int i = 0; i < 4; i++) {
            int s = i * 512 + tid;
            int r = s >> 3, g = s & 7;
            int gs = (g ^ r) & 7;
            gload16(BT + (size_t)(n0 + r) * K + k0 + gs * 8, Bs + r * 64 + g * 8);
        }
    };

    f32x4 acc[8][4] = {};
    stage(0, 0);
    if (NT > 1) stage(1, 1);
    for (int t = 0; t < NT; ++t) {
        if (t + 1 < NT) wait_vm8(); else wait_vm0();
        bar_raw();
        const u16* As = (const u16*)lds[t & 1];
        const u16* Bs = (const u16*)(lds[t & 1] + ABYT);
#pragma unroll
        for (int kk = 0; kk < 2; kk++) {
            int gb = kk * 4 + (lane >> 4);
            s16x8 af[8], bf[4];
#pragma unroll
            for (int mi = 0; mi < 8; mi++) {
                int r = wr * 128 + mi * 16 + (lane & 15);
                af[mi] = *(const s16x8*)&As[r * 64 + ((gb ^ r) & 7) * 8];
            }
#pragma unroll
            for (int ni = 0; ni < 4; ni++) {
                int r = wc * 64 + ni * 16 + (lane & 15);
                bf[ni] = *(const s16x8*)&Bs[r * 64 + ((gb ^ r) & 7) * 8];
            }
#pragma unroll
            for (int mi = 0; mi < 8; mi++)
#pragma unroll
                for (int ni = 0; ni < 4; ni++)
                    acc[mi][ni] = __builtin_amdgcn_mfma_f32_16x16x32_bf16(
                        __builtin_bit_cast(bf16x8, af[mi]), __builtin_bit_cast(bf16x8, bf[ni]),
                        acc[mi][ni], 0, 0, 0);
        }
        bar_raw();
        if (t + 2 < NT) stage(t + 2, t & 1);
    }
    float bvv[4];
#pragma unroll
    for (int ni = 0; ni < 4; ni++) bvv[ni] = bias[n0 + wc * 64 + ni * 16 + (lane & 15)];
#pragma unroll
    for (int mi = 0; mi < 8; mi++) {
        int rb = m0 + wr * 128 + mi * 16 + (lane >> 4) * 4;
#pragma unroll
        for (int j = 0; j < 4; j++) {
            size_t rowo = (size_t)(rb + j) * N;
#pragma unroll
            for (int ni = 0; ni < 4; ni++) {
                int col = n0 + wc * 64 + ni * 16 + (lane & 15);
                float x = acc[mi][ni][j] + bvv[ni];
                __builtin_nontemporal_store(1.f / (1.f + __expf(-x)), &Out[rowo + col]);
            }
        }
    }
}

// ---------------- split-K reduce: H = relu(sum_z P[z] + bias), in-place on P[0] ----------------
__global__ __launch_bounds__(256) void reduce_k(float* __restrict__ P, const float* __restrict__ bias,
                                                int total4, int nz, int colmask4) {
    int i = blockIdx.x * 256 + threadIdx.x;
    int stride = gridDim.x * 256;
    for (; i < total4; i += stride) {
        f32x4 a = ((const f32x4*)P)[i];
        for (int zz = 1; zz < nz; zz++) a += ((const f32x4*)P)[i + (size_t)zz * total4];
        f32x4 b = ((const f32x4*)bias)[i & colmask4];
        a += b;
#pragma unroll
        for (int j = 0; j < 4; j++) a[j] = a[j] > 0.f ? a[j] : 0.f;
        ((f32x4*)P)[i] = a;
    }
}

// ---------------- top-64 of 1024 per row: threshold via bit binary search ----------------
__global__ __launch_bounds__(256) void topk_kernel(const float* __restrict__ H,
                                                   u16* __restrict__ HM,
                                                   float* __restrict__ rowT,
                                                   unsigned* __restrict__ rowFlag) {
    int row = blockIdx.x * 4 + (threadIdx.x >> 6);
    int lane = threadIdx.x & 63;
    const float* hr = H + (size_t)row * 1024;
    float v[16];
#pragma unroll
    for (int i = 0; i < 4; i++) *(f32x4*)&v[i * 4] = *(const f32x4*)(hr + lane * 16 + i * 4);
    unsigned u[16];
#pragma unroll
    for (int i = 0; i < 16; i++) u[i] = __float_as_uint(v[i]);
    unsigned lo = 0;
    for (int b = 30; b >= 0; --b) {
        unsigned cand = lo | (1u << b);
        int c = 0;
#pragma unroll
        for (int i = 0; i < 16; i++) c += (u[i] >= cand);
#pragma unroll
        for (int off = 32; off; off >>= 1) c += __shfl_xor(c, off);
        if (c >= 64) lo = cand;
    }
    unsigned m2 = 0;
#pragma unroll
    for (int i = 0; i < 16; i++)
        if (u[i] < lo && u[i] > m2) m2 = u[i];
#pragma unroll
    for (int off = 32; off; off >>= 1) {
        unsigned o = __shfl_xor(m2, off);
        if (o > m2) m2 = o;
    }
    u16 o16[16];
#pragma unroll
    for (int i = 0; i < 16; i++) o16[i] = (u[i] >= lo) ? f2bf_rn(v[i]) : (u16)0;
    unsigned p[8];
#pragma unroll
    for (int i = 0; i < 8; i++) p[i] = (unsigned)o16[2 * i] | ((unsigned)o16[2 * i + 1] << 16);
    u16* dst = HM + (size_t)row * 1024 + lane * 16;
    *(uint4*)dst = make_uint4(p[0], p[1], p[2], p[3]);
    *(uint4*)(dst + 8) = make_uint4(p[4], p[5], p[6], p[7]);
    if (lane == 0) {
        rowT[row] = __uint_as_float(lo);
        float t = __uint_as_float(lo), s = __uint_as_float(m2);
        rowFlag[row] = (lo != 0u) && (t - s < SEL_BAND);
    }
}

// ---------------- fp64 fix-up: 256 thr, wave-per-candidate, 4-chain dots ----------------
__global__ __launch_bounds__(256) void fixup_kernel(const float* __restrict__ H,
                                                    const float* __restrict__ X,
                                                    const float* __restrict__ W,  // [1024][12288] f32 (We1^T)
                                                    const float* __restrict__ be1,
                                                    const float* __restrict__ rowT,
                                                    const unsigned* __restrict__ rowFlag,
                                                    u16* __restrict__ HM) {
    int row = blockIdx.x;
    if (!rowFlag[row]) return;
    int tid = threadIdx.x, lane = tid & 63, wv = tid >> 6;
    float Tf = rowT[row];
    const float* hr = H + (size_t)row * 1024;
    f32x4 v = *(const f32x4*)(hr + tid * 4);
    __shared__ int bidx[64];
    __shared__ float bval[64];
    __shared__ double dval[64];
    __shared__ int cnt, csh;
    if (tid == 0) { cnt = 0; csh = 0; }
    __syncthreads();
    int myS = 0;
#pragma unroll
    for (int i = 0; i < 4; i++) {
        float x = v[i];
        if (fabsf(x - Tf) <= SEL_BAND) {
            int p = atomicAdd(&cnt, 1);
            if (p < 64) { bidx[p] = tid * 4 + i; bval[p] = x; }
        }
        myS += (x > Tf + SEL_BAND);
    }
#pragma unroll
    for (int off = 32; off; off >>= 1) myS += __shfl_xor(myS, off);
    if (lane == 0) atomicAdd(&csh, myS);
    __syncthreads();
    int nb = cnt < 64 ? cnt : 64;
    if (nb < 2) return;
    int kband = 64 - csh;
    const float* xr = X + (size_t)row * 12288;
    for (int e = wv; e < nb; e += 4) {
        const float* wp = W + (size_t)bidx[e] * 12288;
        double s0 = 0, s1 = 0, s2 = 0, s3 = 0;
        for (int k0 = 0; k0 < 12288; k0 += 256) {
            s0 += (double)xr[k0 + lane]       * (double)wp[k0 + lane];
            s1 += (double)xr[k0 + 64 + lane]  * (double)wp[k0 + 64 + lane];
            s2 += (double)xr[k0 + 128 + lane] * (double)wp[k0 + 128 + lane];
            s3 += (double)xr[k0 + 192 + lane] * (double)wp[k0 + 192 + lane];
        }
        double s = (s0 + s1) + (s2 + s3);
#pragma unroll
        for (int off = 32; off; off >>= 1) s += __shfl_xor(s, off);
        if (lane == 0) dval[e] = s + (double)be1[bidx[e]];
    }
    __syncthreads();
    if (tid < nb) {
        double me = dval[tid];
        int j = bidx[tid];
        int rank = 0;
        for (int f = 0; f < nb; f++) {
            double df = dval[f];
            rank += (df > me) || (df == me && bidx[f] < j);
        }
        HM[(size_t)row * 1024 + j] = (rank < kband) ? f2bf_rn(bval[tid]) : (u16)0;
    }
}

extern "C" void kernel_launch(void* const* d_in, const int* in_sizes, int n_in,
                              void* d_out, int out_size, void* d_ws, size_t ws_size,
                              hipStream_t stream) {
    const float* X   = (const float*)d_in[0];
    const float* We1 = (const float*)d_in[1];
    const float* be1 = (const float*)d_in[2];
    const float* Wd1 = (const float*)d_in[3];
    const float* bd1 = (const float*)d_in[4];
    const float* Wd2 = (const float*)d_in[5];
    const float* bd2 = (const float*)d_in[6];

    // workspace tiers: base 136.3 MB (proven) + (SPLITK-1) x 16.8 MB partials
    int splitk = (ws_size >= 187100000ull) ? 4 : (ws_size >= 153600000ull) ? 2 : 1;

    char* ws = (char*)d_ws;
    size_t off = 0;
    auto alloc = [&](size_t bytes) { void* p = ws + off; off += (bytes + 255) & ~(size_t)255; return p; };
    u16* W1hT    = (u16*)alloc(12288ull * 1024 * 2);   // fp16 bits x256, [1024][12288]
    float* We1Tf = (float*)alloc(12288ull * 1024 * 4); // f32 [1024][12288] for fixup
    u16* Wd1T    = (u16*)alloc(1024ull * 1024 * 2);
    u16* Wd2T    = (u16*)alloc(1024ull * 12288 * 2);
    float* Hbuf  = (float*)alloc((size_t)splitk * 4096 * 1024 * 4);  // partial[0] == Hbuf
    u16* HM      = (u16*)alloc(4096ull * 1024 * 2);
    u16* Dbf     = (u16*)alloc(4096ull * 1024 * 2);
    float* rowT  = (float*)alloc(4096 * 4);
    unsigned* rowFlag = (unsigned*)alloc(4096 * 4);

    dim3 tb(32, 8);
    tr_hf<<<dim3(32, 384), tb, 0, stream>>>(We1, 12288, 1024, W1hT, We1Tf);
    tr_bf16<<<dim3(32, 32), tb, 0, stream>>>(Wd1, 1024, 1024, Wd1T);
    tr_bf16<<<dim3(384, 32), tb, 0, stream>>>(Wd2, 1024, 12288, Wd2T);

    if (splitk == 4) {
        gemm1_k<4><<<dim3(32, 4, 4), 512, 0, stream>>>(X, W1hT, be1, Hbuf, 4096, 1024, 12288);
        reduce_k<<<2048, 256, 0, stream>>>(Hbuf, be1, 4096 * 1024 / 4, 4, 255);
    } else if (splitk == 2) {
        gemm1_k<2><<<dim3(32, 4, 2), 512, 0, stream>>>(X, W1hT, be1, Hbuf, 4096, 1024, 12288);
        reduce_k<<<2048, 256, 0, stream>>>(Hbuf, be1, 4096 * 1024 / 4, 2, 255);
    } else {
        gemm1_k<1><<<dim3(32, 4), 512, 0, stream>>>(X, W1hT, be1, Hbuf, 4096, 1024, 12288);
    }
    topk_kernel<<<1024, 256, 0, stream>>>(Hbuf, HM, rowT, rowFlag);
    fixup_kernel<<<4096, 256, 0, stream>>>(Hbuf, X, We1Tf, be1, rowT, rowFlag, HM);
    gemm2_k<<<dim3(64, 8), 256, 0, stream>>>(HM, Wd1T, bd1, Dbf, 4096, 1024, 1024);
    gemm3_k<<<dim3(16, 48), 512, 0, stream>>>(Dbf, Wd2T, bd2, (float*)d_out, 4096, 12288, 1024);
}